// Round 11
// baseline (294.596 us; speedup 1.0000x reference)
//
#include <hip/hip_runtime.h>
#include <hip/hip_bf16.h>

#define T_ 4
#define B_ 4
#define N_ 16384
#define KALL_ 4
#define F_ 16384
#define ORD_ 3
#define DIN_ 4
#define H_ 64
#define H3_ 192
#define DE_ 4
#define STR 72   // padded bf16 leading-dim for MFMA A/B LDS tiles (k_head)
#define NE_ 49152  // F*ORD edges

typedef __attribute__((ext_vector_type(8))) short s16x8;
typedef __attribute__((ext_vector_type(4))) float f32x4;
typedef __attribute__((ext_vector_type(2))) float f32x2;
typedef unsigned long long u64;

static __device__ __forceinline__ float b2f(unsigned short u) {
  union { unsigned u; float f; } x; x.u = ((unsigned)u) << 16; return x.f;
}
static __device__ __forceinline__ unsigned short f2b(float f) {
  __hip_bfloat16 h = __float2bfloat16(f);  // RNE
  union { __hip_bfloat16 h; unsigned short u; } x; x.h = h; return x.u;
}
static __device__ __forceinline__ float sigm_fast(float v) {
  return __builtin_amdgcn_rcpf(1.f + __expf(-v));
}
static __device__ __forceinline__ float tanh_fast(float v) {
  float e = __expf(2.f * v);
  return 1.f - 2.f * __builtin_amdgcn_rcpf(e + 1.f);
}

// ---------------------------------------------------------------------------
// Fused prep: CSR count (blocks 0..191) + Wh permute/convert (192..239) +
// attn-weight transpose/convert (240..303) + W1 transpose/convert (304..319).
// ---------------------------------------------------------------------------
__global__ __launch_bounds__(256) void k_prep(
    const int* __restrict__ idx, int* __restrict__ cnt,
    const float* __restrict__ Wh, unsigned short* __restrict__ whTg,
    const float* __restrict__ Wq, const float* __restrict__ Wk,
    const float* __restrict__ Wv, const float* __restrict__ Wo,
    unsigned short* __restrict__ wT,
    const float* __restrict__ W1, unsigned short* __restrict__ w1Tg) {
  const int b = blockIdx.x, tid = threadIdx.x;
  if (b < 192) {
    int e = b * 256 + tid;
    if (e < NE_) atomicAdd(&cnt[idx[e]], 1);
  } else if (b < 240) {
    // whTg[rr*64+k], rr=16*ct+c, ct=g*4+cg holds Wh[k][g*64+4*c+cg]
    int i = (b - 192) * 256 + tid;        // 48*256 = 12288
    int rr = i >> 6, k = i & 63;
    int ct = rr >> 4, c = rr & 15;
    int g = ct >> 2, cg = ct & 3;
    whTg[i] = f2b(Wh[k * H3_ + g * 64 + 4 * c + cg]);
  } else if (b < 304) {
    // wT[m][col][k] so a per-lane B-fragment is one contiguous 16-B load
    int i = (b - 240) * 256 + tid;        // 64*256 = 16384
    int m = i >> 12, col = (i >> 6) & 63, k = i & 63;
    const float* Wm = (m == 0) ? Wq : (m == 1) ? Wk : (m == 2) ? Wv : Wo;
    wT[i] = f2b(Wm[k * 64 + col]);
  } else {
    // w1Tg[col*64+k] = W1[k][col], k<64 (extra rows handled via hEx)
    int i = (b - 304) * 256 + tid;        // 16*256 = 4096
    int col = i >> 6, k = i & 63;
    w1Tg[i] = f2b(W1[k * 64 + col]);
  }
}

__global__ __launch_bounds__(256) void k_csr_scan(
    const int* __restrict__ cnt, int* __restrict__ offs, int* __restrict__ cursor) {
  __shared__ int part[256];
  __shared__ int base[256];
  int t = threadIdx.x;
  int s = 0;
  for (int j = 0; j < 64; ++j) s += cnt[t * 64 + j];
  part[t] = s;
  __syncthreads();
  if (t == 0) {
    int run = 0;
    for (int i = 0; i < 256; ++i) { base[i] = run; run += part[i]; }
  }
  __syncthreads();
  int run = base[t];
  for (int j = 0; j < 64; ++j) {
    offs[t * 64 + j] = run;
    cursor[t * 64 + j] = run;
    run += cnt[t * 64 + j];
  }
  if (t == 255) offs[N_] = run;
}
__global__ __launch_bounds__(256) void k_csr_fill(
    const int* __restrict__ idx, int* __restrict__ cursor, int* __restrict__ elist) {
  int e = blockIdx.x * 256 + threadIdx.x;
  if (e < NE_) {
    int pos = atomicAdd(&cursor[idx[e]], 1);
    elist[pos] = e;
  }
}

// ---------------------------------------------------------------------------
// Kernel 1: GRU v5 (verified R8/R10: VGPR 112, 43-46 µs). Barrier-free
// t-loop, carry f32 in regs, permuted-column WhT, two cg-halves with
// sched_barrier keeping the halves' register sets apart.
// ---------------------------------------------------------------------------
__global__ __launch_bounds__(256) void k_gru(
    const float* __restrict__ h0,
    const float* __restrict__ x,
    const int* __restrict__ dones,
    const unsigned short* __restrict__ whTg,
    const float* __restrict__ Wi,
    const float* __restrict__ bi,
    const float* __restrict__ bhn,
    unsigned short* __restrict__ hs,     // [T*B,N,H] bf16
    float* __restrict__ hfin)            // [B,N,H] f32
{
  __shared__ __align__(16) short whT[H3_ * 72];    // 27648 B, bf16 B-tiles
  __shared__ __align__(16) short carry[H_ * 72];   // 9216 B, bf16 A-tiles
  __shared__ float wiS[5 * H3_];                   // 3840 B: Wi rows 0..3, bi row 4

  const int tid = threadIdx.x;
  const int lane = tid & 63;
  const int w = tid >> 6;
  const int c15 = lane & 15;
  const int hi4 = lane >> 4;
  const int bid = blockIdx.x;
  const int b = bid >> 8;
  const int nbase = (bid & 255) * 64;
  const int hb = 4 * c15;                 // contiguous h-base of this lane

  // stage whT (pre-converted, permuted): 6 x 16-byte copies per thread
#pragma unroll
  for (int c = 0; c < 6; ++c) {
    int lin = (c * 256 + tid) * 8;        // element index, 8 bf16 per copy
    int row = lin >> 6, col = lin & 63;
    *(s16x8*)&whT[row * 72 + col] = *(const s16x8*)&whTg[lin];
  }
  // stage Wi (f32) + bias row
  for (int i = tid; i < 5 * H3_; i += 256)
    wiS[i] = (i < 4 * H3_) ? Wi[i] : bi[i - 4 * H3_];

  // carry state in registers + bf16 LDS copy (wave-private rows)
  f32x4 cf[4];
#pragma unroll
  for (int r = 0; r < 4; ++r) {
    int row = 16 * w + 4 * hi4 + r;
    cf[r] = *(const f32x4*)&h0[(size_t)(b * N_ + nbase + row) * H_ + hb];
    u64 pk = 0;
#pragma unroll
    for (int e = 0; e < 4; ++e) pk |= (u64)f2b(cf[r][e]) << (16 * e);
    *(u64*)&carry[row * 72 + hb] = pk;
  }

  float bhnr[4];
#pragma unroll
  for (int cg = 0; cg < 4; ++cg) bhnr[cg] = bhn[hb + cg];

  // hoisted dones decode -> bitmask (no runtime-indexed array: rule #20)
  unsigned dmask = 0;
  {
    bool word = true;
#pragma unroll
    for (int i = 0; i < 16; ++i) {
      int v = dones[i];
      if (v != 0 && v != 1 && v != 0x3F800000) word = false;
    }
#pragma unroll
    for (int t = 0; t < T_; ++t) {
      int tb = t * B_ + b;
      bool d = word ? (dones[tb] != 0) : (((const unsigned char*)dones)[tb] != 0);
      if (d) dmask |= (1u << t);
    }
  }

  __syncthreads();   // whT/wiS visible; after this the t-loop is barrier-free

  const int rowA = 16 * w + c15;
#pragma unroll 1
  for (int t = 0; t < T_; ++t) {
    if ((dmask >> t) & 1u) {
#pragma unroll
      for (int r = 0; r < 4; ++r) {
        cf[r] = (f32x4){0.f, 0.f, 0.f, 0.f};
        *(u64*)&carry[(16 * w + 4 * hi4 + r) * 72 + hb] = 0ull;
      }
    }

    // A-fragments for this t (carry rows are wave-private; DS ops in-order)
    s16x8 af0 = *(const s16x8*)&carry[rowA * 72 + hi4 * 8];
    s16x8 af1 = *(const s16x8*)&carry[rowA * 72 + 32 + hi4 * 8];

    // x for all 4 rows, loaded early (independent HBM loads)
    f32x4 xv[4];
#pragma unroll
    for (int r = 0; r < 4; ++r) {
      const int node = nbase + 16 * w + 4 * hi4 + r;
      xv[r] = *(const f32x4*)&x[(size_t)((t * B_ + b) * N_ + node) * DIN_];
    }

    // two cg-halves: hh covers output columns hb+2*hh .. hb+2*hh+1
#pragma unroll
    for (int hh = 0; hh < 2; ++hh) {
      f32x4 acc[6];                       // [g*2+c2], only 24 VGPR live
#pragma unroll
      for (int j = 0; j < 6; ++j) acc[j] = (f32x4){0.f, 0.f, 0.f, 0.f};
#pragma unroll
      for (int j = 0; j < 6; ++j) {
        const int ct = (j >> 1) * 4 + 2 * hh + (j & 1);
        acc[j] = __builtin_amdgcn_mfma_f32_16x16x32_bf16(
            af0, *(const s16x8*)&whT[(16 * ct + c15) * 72 + hi4 * 8], acc[j], 0, 0, 0);
      }
#pragma unroll
      for (int j = 0; j < 6; ++j) {
        const int ct = (j >> 1) * 4 + 2 * hh + (j & 1);
        acc[j] = __builtin_amdgcn_mfma_f32_16x16x32_bf16(
            af1, *(const s16x8*)&whT[(16 * ct + c15) * 72 + 32 + hi4 * 8], acc[j], 0, 0, 0);
      }
      const int hb2 = hb + 2 * hh;
#pragma unroll
      for (int r = 0; r < 4; ++r) {
        f32x2 gi[3];
#pragma unroll
        for (int g = 0; g < 3; ++g) {
          f32x2 s = *(const f32x2*)&wiS[4 * H3_ + g * 64 + hb2];   // bias
#pragma unroll
          for (int kk = 0; kk < 4; ++kk) {
            f32x2 wv = *(const f32x2*)&wiS[kk * H3_ + g * 64 + hb2];
            s += xv[r][kk] * wv;
          }
          gi[g] = s;
        }
#pragma unroll
        for (int c2 = 0; c2 < 2; ++c2) {
          const int cg = 2 * hh + c2;
          float rg = sigm_fast(gi[0][c2] + acc[c2][r]);
          float zg = sigm_fast(gi[1][c2] + acc[2 + c2][r]);
          float ng = tanh_fast(gi[2][c2] + rg * (acc[4 + c2][r] + bhnr[cg]));
          float nc = zg * (cf[r][cg] - ng) + ng;   // (1-z)n + z*c
          cf[r][cg] = nc;
        }
      }
      __builtin_amdgcn_sched_barrier(0);  // keep the two halves' regs apart
    }

    // single store phase per t from cf
#pragma unroll
    for (int r = 0; r < 4; ++r) {
      const int row = 16 * w + 4 * hi4 + r;
      const int node = nbase + row;
      u64 pk = 0;
#pragma unroll
      for (int e = 0; e < 4; ++e) pk |= (u64)f2b(cf[r][e]) << (16 * e);
      *(u64*)&hs[(size_t)((t * B_ + b) * N_ + node) * H_ + hb] = pk;
      *(u64*)&carry[row * 72 + hb] = pk;
      if (t == T_ - 1)
        *(f32x4*)&hfin[(size_t)(b * N_ + node) * H_ + hb] = cf[r];
    }
    // no __syncthreads: carry rows are wave-private, whT/wiS read-only
  }
}

// ---------------------------------------------------------------------------
// Kernel 2 v8: bufrag ELIMINATED. Algebra of the old swizzled store/read
// shows afr[rt][ks] for lane (c15,hi4) == hs[idxs[16rt+c15]*H + ks*32 +
// hi4*8 ..+8] — one contiguous 16-B global load. So each lane gathers its
// MFMA A-fragment directly (row offsets are slice-invariant; only the hp
// base changes). Removes 3 u64 LDS stores + 6 ds_read_b128 + swizzle math
// per iteration; waves 1-3 hit L1 on wave 0's lines (same rows). Register
// prefetch kept: afr overwritten with next-slice loads after the MFMAs.
// LDS 26.1 -> 19.8 KB (8 blocks/CU cap). Barriers: {writes -> B2 ->
// softmax -> B3}, B3 skipped on last iter (15 total).
// ---------------------------------------------------------------------------
__global__ __launch_bounds__(256) void k_attn(
    const int tb0,
    const unsigned short* __restrict__ hs,    // [T*B,N,H] bf16
    const int* __restrict__ indices,
    const unsigned short* __restrict__ wT,    // [4][64][64] bf16
    const float* __restrict__ bq, const float* __restrict__ bk,
    const float* __restrict__ bv,
    unsigned short* __restrict__ a_edge)      // [8,NE,H] bf16 — o values
{
  __shared__ __align__(8) unsigned short qsB[48 * 68]; // 6528 B
  __shared__ __align__(8) unsigned short ksB[48 * 68]; // 6528 B
  __shared__ __align__(8) unsigned short vsB[48 * 68]; // 6528 B
  __shared__ int idxs[48];

  const int tid = threadIdx.x;
  const int lane = tid & 63;
  const int w = tid >> 6;
  const int c15 = lane & 15;
  const int hi4 = lane >> 4;
  const int bid = blockIdx.x;
  const int col = 16 * w + c15;

  if (tid < 48) idxs[tid] = indices[bid * 48 + tid];

  // per-wave B fragments: one contiguous 16-B load each from wT
  s16x8 wB[3][2];
#pragma unroll
  for (int m = 0; m < 3; ++m)
#pragma unroll
    for (int ks = 0; ks < 2; ++ks)
      wB[m][ks] = *(const s16x8*)&wT[(m * 64 + col) * 64 + ks * 32 + hi4 * 8];
  const float bq_c = bq[col], bk_c = bk[col], bv_c = bv[col];
  __syncthreads();                            // idxs ready

  // slice-invariant A-fragment element offsets (this lane's 3 rows)
  int rowoff[3];
#pragma unroll
  for (int rt = 0; rt < 3; ++rt)
    rowoff[rt] = idxs[16 * rt + c15] * H_ + hi4 * 8;

  // preload afr for slice 0
  s16x8 afr[3][2];
  {
    const unsigned short* hp = hs + (size_t)tb0 * (N_ * H_);
#pragma unroll
    for (int rt = 0; rt < 3; ++rt)
#pragma unroll
      for (int ks = 0; ks < 2; ++ks)
        afr[rt][ks] = *(const s16x8*)&hp[rowoff[rt] + ks * 32];
  }

  for (int it = 0; it < 8; ++it) {
    // ---- QKV projections from register A-frags -> bf16 LDS ----
#pragma unroll
    for (int rt = 0; rt < 3; ++rt) {
      f32x4 aq = (f32x4){0.f, 0.f, 0.f, 0.f};
      aq = __builtin_amdgcn_mfma_f32_16x16x32_bf16(afr[rt][0], wB[0][0], aq, 0, 0, 0);
      aq = __builtin_amdgcn_mfma_f32_16x16x32_bf16(afr[rt][1], wB[0][1], aq, 0, 0, 0);
#pragma unroll
      for (int r = 0; r < 4; ++r)
        qsB[(16 * rt + hi4 * 4 + r) * 68 + col] = f2b((aq[r] + bq_c) * 0.25f);
    }
#pragma unroll
    for (int rt = 0; rt < 3; ++rt) {
      f32x4 ak = (f32x4){0.f, 0.f, 0.f, 0.f};
      ak = __builtin_amdgcn_mfma_f32_16x16x32_bf16(afr[rt][0], wB[1][0], ak, 0, 0, 0);
      ak = __builtin_amdgcn_mfma_f32_16x16x32_bf16(afr[rt][1], wB[1][1], ak, 0, 0, 0);
#pragma unroll
      for (int r = 0; r < 4; ++r)
        ksB[(16 * rt + hi4 * 4 + r) * 68 + col] = f2b(ak[r] + bk_c);
    }
#pragma unroll
    for (int rt = 0; rt < 3; ++rt) {
      f32x4 av = (f32x4){0.f, 0.f, 0.f, 0.f};
      av = __builtin_amdgcn_mfma_f32_16x16x32_bf16(afr[rt][0], wB[2][0], av, 0, 0, 0);
      av = __builtin_amdgcn_mfma_f32_16x16x32_bf16(afr[rt][1], wB[2][1], av, 0, 0, 0);
#pragma unroll
      for (int r = 0; r < 4; ++r)
        vsB[(16 * rt + hi4 * 4 + r) * 68 + col] = f2b(av[r] + bv_c);
    }
    // prefetch next slice's A-frags into the same registers (MFMAs above
    // already consumed the old values; loads land during softmax+barriers)
    if (it < 7) {
      const unsigned short* hp = hs + (size_t)(tb0 + it + 1) * (N_ * H_);
#pragma unroll
      for (int rt = 0; rt < 3; ++rt)
#pragma unroll
        for (int ks = 0; ks < 2; ++ks)
          afr[rt][ks] = *(const s16x8*)&hp[rowoff[rt] + ks * 32];
    }
    __syncthreads();                          // B2: qkv ready

    // ---- softmax + PV: thread = (f, head, dq); o -> global directly ----
    {
      int f = tid >> 4, head = (tid >> 2) & 3, dq = tid & 3;
      int colb = head * 16 + dq * 4;
      float qv[3][4], kv[3][4], vv[3][4];
#pragma unroll
      for (int qi = 0; qi < 3; ++qi) {
        int base = (3 * f + qi) * 68 + colb;
        u64 uq = *(const u64*)&qsB[base];
        u64 uk = *(const u64*)&ksB[base];
        u64 uv = *(const u64*)&vsB[base];
#pragma unroll
        for (int e = 0; e < 4; ++e) {
          qv[qi][e] = b2f((unsigned short)(uq >> (16 * e)));
          kv[qi][e] = b2f((unsigned short)(uk >> (16 * e)));
          vv[qi][e] = b2f((unsigned short)(uv >> (16 * e)));
        }
      }
      float s[3][3];
#pragma unroll
      for (int qi = 0; qi < 3; ++qi)
#pragma unroll
        for (int ki = 0; ki < 3; ++ki) {
          float a = qv[qi][0] * kv[ki][0] + qv[qi][1] * kv[ki][1]
                  + qv[qi][2] * kv[ki][2] + qv[qi][3] * kv[ki][3];
          a += __shfl_xor(a, 1, 64);
          a += __shfl_xor(a, 2, 64);
          s[qi][ki] = a;
        }
      const size_t abase = (size_t)it * NE_ + (size_t)bid * 48;
#pragma unroll
      for (int qi = 0; qi < 3; ++qi) {
        float mx = fmaxf(s[qi][0], fmaxf(s[qi][1], s[qi][2]));
        float e0 = __expf(s[qi][0] - mx), e1 = __expf(s[qi][1] - mx), e2 = __expf(s[qi][2] - mx);
        float inv = 1.f / (e0 + e1 + e2);
        e0 *= inv; e1 *= inv; e2 *= inv;
        int row = 3 * f + qi;
        u64 pack = 0;
#pragma unroll
        for (int e = 0; e < 4; ++e) {
          float o = e0 * vv[0][e] + e1 * vv[1][e] + e2 * vv[2][e];
          pack |= (u64)f2b(o) << (16 * e);
        }
        *(u64*)&a_edge[(abase + row) * H_ + colb] = pack;
      }
    }
    if (it < 7) __syncthreads();              // B3: softmax reads done
  }
}

// ---------------------------------------------------------------------------
// Kernel 3 v4 (verified R8): u64 gather, rcp, pre-converted W1 staging,
// Wo absorbed as extra MFMA GEMM.
// ---------------------------------------------------------------------------
__global__ __launch_bounds__(256) void k_head(
    const int tb0,
    const unsigned short* __restrict__ a_edge, // [8,NE,H] bf16 — o values
    const int* __restrict__ offs, const int* __restrict__ elist,
    const unsigned short* __restrict__ wT,     // [4][64][64]; m=3 is Wo
    const float* __restrict__ bo,
    const float* __restrict__ extra,
    const float* __restrict__ W1, const float* __restrict__ b1,
    const unsigned short* __restrict__ w1Tg,   // [64][64] bf16 transposed
    const float* __restrict__ W2, const float* __restrict__ b2,
    float* __restrict__ yg,                    // [T*B,KALL,H] f32, pre-zeroed
    float* __restrict__ logit)                 // [T,B,N] f32
{
  __shared__ __align__(16) short w1T[64 * STR];
  __shared__ __align__(16) short arow[64 * STR];
  __shared__ int offsS[65];
  __shared__ int eidS[512];
  __shared__ float hEx[64];
  __shared__ float w2s[64];
  __shared__ float hasES[64];
  __shared__ float red[4][64];

  const int tid = threadIdx.x;
  const int lane = tid & 63;
  const int w = tid >> 6;
  const int c15 = lane & 15;
  const int hi4 = lane >> 4;
  const int bid = blockIdx.x;
  const int ls = bid >> 8;             // local slice 0..7
  const int tb = tb0 + ls;
  const int nbase = (bid & 255) * 64;
  const int kall = nbase >> 12;

  // stage w1T from pre-converted w1Tg: 2 x 16-B copies per thread
#pragma unroll
  for (int c = 0; c < 2; ++c) {
    int lin = (c * 256 + tid) * 8;
    int row = lin >> 6, col = lin & 63;
    *(s16x8*)&w1T[row * STR + col] = *(const s16x8*)&w1Tg[lin];
  }
  if (tid < 65) offsS[tid] = offs[nbase + tid];
  if (tid < 64) {
    float s = b1[tid];
#pragma unroll
    for (int e = 0; e < 4; ++e)
      s += extra[(tb * KALL_ + kall) * DE_ + e] * W1[(64 + e) * 64 + tid];
    hEx[tid] = s;
    w2s[tid] = W2[tid];
  }
  // Wo B-fragments + bias in registers (coalesced 16-B loads from wT)
  s16x8 wo_b[2][4];
  float boc[4];
#pragma unroll
  for (int ct = 0; ct < 4; ++ct) {
    boc[ct] = bo[16 * ct + c15];
#pragma unroll
    for (int ks = 0; ks < 2; ++ks)
      wo_b[ks][ct] = *(const s16x8*)&wT[(192 + 16 * ct + c15) * 64 + ks * 32 + hi4 * 8];
  }
  // edge-range staging
  const int ebeg = offs[nbase];
  const int ecnt = offs[nbase + 64] - ebeg;
  const bool fast = (ecnt <= 512);
  if (tid == 0) eidS[0] = 0;           // safe dup slot even when ecnt == 0
  if (fast) {
    for (int j = tid; j < ecnt; j += 256) eidS[j] = elist[ebeg + j];
  }
  __syncthreads();

  const size_t ebase = (size_t)ls * NE_;
  if (fast) {
    const int cg = tid & 15;
#pragma unroll
    for (int ku = 0; ku < 4; ++ku) {
      const int r = ku * 16 + (tid >> 4);
      const int beg = offsS[r] - ebeg, end = offsS[r + 1] - ebeg;
      const int cnt = end - beg;
      const float inv = __builtin_amdgcn_rcpf(fmaxf((float)cnt, 1.f));
      f32x4 s = (f32x4){0.f, 0.f, 0.f, 0.f};
#pragma unroll
      for (int u = 0; u < 8; ++u) {
        int p = beg + u;
        bool valid = p < end;
        int pc = valid ? p : 0;        // dup -> eidS[0] row, L1-hot
        u64 v = *(const u64*)&a_edge[(ebase + eidS[pc]) * H_ + cg * 4];
        if (!valid) v = 0;             // 2 cndmasks; b2f(0)=0
        s[0] += b2f((unsigned short)v);
        s[1] += b2f((unsigned short)(v >> 16));
        s[2] += b2f((unsigned short)(v >> 32));
        s[3] += b2f((unsigned short)(v >> 48));
      }
      for (int p = beg + 8; p < end; ++p) {        // rare tail (cnt > 8)
        u64 v = *(const u64*)&a_edge[(ebase + eidS[p]) * H_ + cg * 4];
        s[0] += b2f((unsigned short)v);
        s[1] += b2f((unsigned short)(v >> 16));
        s[2] += b2f((unsigned short)(v >> 32));
        s[3] += b2f((unsigned short)(v >> 48));
      }
      u64 pk = 0;
#pragma unroll
      for (int e = 0; e < 4; ++e) pk |= (u64)f2b(s[e] * inv) << (16 * e);
      *(u64*)&arow[r * STR + cg * 4] = pk;
      if (cg == 0) hasES[r] = (cnt > 0) ? 1.f : 0.f;
    }
  } else {
    // fallback: direct-global dynamic loop (never taken for this input size)
    for (int r = w; r < 64; r += 4) {
      const int beg = offsS[r], end = offsS[r + 1];
      float s = 0.f;
      for (int p = beg; p < end; ++p)
        s += b2f(a_edge[(ebase + elist[p]) * H_ + lane]);
      float val = s / fmaxf((float)(end - beg), 1.f);
      arow[r * STR + lane] = (short)f2b(val);
      if (lane == 0) hasES[r] = (end > beg) ? 1.f : 0.f;
    }
  }
  __syncthreads();

  // ---- Wo GEMM: o-mean -> y; overwrite arow in place (wave-private rows,
  // same-wave DS ordering makes reads-before-writes safe) ----
  f32x4 acco[4];
#pragma unroll
  for (int ct = 0; ct < 4; ++ct) acco[ct] = (f32x4){0.f, 0.f, 0.f, 0.f};
#pragma unroll
  for (int ks = 0; ks < 2; ++ks) {
    int kb = ks * 32 + hi4 * 8;
    s16x8 af = *(const s16x8*)&arow[(16 * w + c15) * STR + kb];
#pragma unroll
    for (int ct = 0; ct < 4; ++ct)
      acco[ct] = __builtin_amdgcn_mfma_f32_16x16x32_bf16(af, wo_b[ks][ct], acco[ct], 0, 0, 0);
  }
  float sumy[4] = {0.f, 0.f, 0.f, 0.f};
#pragma unroll
  for (int r = 0; r < 4; ++r) {
    const int rowr = 16 * w + hi4 * 4 + r;
    const float hase = hasES[rowr];
#pragma unroll
    for (int ct = 0; ct < 4; ++ct) {
      float y = acco[ct][r] + hase * boc[ct];
      arow[rowr * STR + 16 * ct + c15] = (short)f2b(y);
      sumy[ct] += y;
    }
  }
#pragma unroll
  for (int ct = 0; ct < 4; ++ct) {
    sumy[ct] += __shfl_xor(sumy[ct], 16, 64);
    sumy[ct] += __shfl_xor(sumy[ct], 32, 64);
  }
  if (hi4 == 0) {
#pragma unroll
    for (int ct = 0; ct < 4; ++ct) red[w][16 * ct + c15] = sumy[ct];
  }

  // ---- W1 GEMM (reads own wave's arow_y rows; no barrier needed) ----
  f32x4 acc[4];
#pragma unroll
  for (int ct = 0; ct < 4; ++ct) acc[ct] = (f32x4){0.f, 0.f, 0.f, 0.f};
#pragma unroll
  for (int ks = 0; ks < 2; ++ks) {
    int kb = ks * 32 + hi4 * 8;
    s16x8 af = *(const s16x8*)&arow[(16 * w + c15) * STR + kb];
#pragma unroll
    for (int ct = 0; ct < 4; ++ct) {
      s16x8 bfr = *(const s16x8*)&w1T[(16 * ct + c15) * STR + kb];
      acc[ct] = __builtin_amdgcn_mfma_f32_16x16x32_bf16(af, bfr, acc[ct], 0, 0, 0);
    }
  }
  const float b2v = b2[0];
#pragma unroll
  for (int r = 0; r < 4; ++r) {
    float s = 0.f;
#pragma unroll
    for (int ct = 0; ct < 4; ++ct) {
      int colc = 16 * ct + c15;
      s += fmaxf(acc[ct][r] + hEx[colc], 0.f) * w2s[colc];
    }
    s += __shfl_xor(s, 1, 64);
    s += __shfl_xor(s, 2, 64);
    s += __shfl_xor(s, 4, 64);
    s += __shfl_xor(s, 8, 64);
    if (c15 == 0)
      logit[tb * N_ + nbase + 16 * w + hi4 * 4 + r] = s + b2v;
  }
  __syncthreads();
  if (tid < 64) {
    float sv = red[0][tid] + red[1][tid] + red[2][tid] + red[3][tid];
    atomicAdd(&yg[(tb * KALL_ + kall) * H_ + tid], sv);
  }
}

// ---------------------------------------------------------------------------
// Kernel 4: value head + h_global passthrough (f32)
// ---------------------------------------------------------------------------
__global__ __launch_bounds__(256) void k_final(
    const float* __restrict__ yg,
    const float* __restrict__ extra,
    const float* __restrict__ Wv1, const float* __restrict__ bv1,
    const float* __restrict__ hg_in,
    float* __restrict__ value_out,
    float* __restrict__ hg_out)
{
  const int tid = threadIdx.x;
  if (tid < 16) {
    const float bv = bv1[0];
    float v = 0.f;
    for (int kall = 0; kall < 4; ++kall) {
      float s = bv;
      for (int hh = 0; hh < 64; ++hh)
        s += (yg[(tid * KALL_ + kall) * H_ + hh] * (1.f / 4096.f)) * Wv1[hh];
      for (int e = 0; e < 4; ++e)
        s += extra[(tid * KALL_ + kall) * DE_ + e] * Wv1[64 + e];
      v += s;
    }
    value_out[tid] = v;
  }
  for (int i = tid; i < 1024; i += 256) hg_out[i] = hg_in[i];
}

// ---------------------------------------------------------------------------
// Workspace layout (84.4 MB, proven safe):
//   yg     @ 0        : 16,384 B    f32 [T*B,KALL,H]
//   cnt    @ 16384    : 65,536 B    int [N]
//   offs   @ 81920    : 65,540 B    int [N+1]
//   cursor @ 147584   : 65,536 B    int [N]
//   elist  @ 213120   : 196,608 B   int [NE]
//   whTg   @ 409728   : 24,576 B    bf16 [192][64] permuted WhT
//   wT     @ 434304   : 32,768 B    bf16 [4][64][64] transposed Wq/Wk/Wv/Wo
//   w1Tg   @ 467072   : 8,192 B     bf16 [64][64] transposed W1
//   hs     @ 524288   : 33,554,432 B bf16 [T*B,N,H]
//   a_edge @ 34078720 : 50,331,648 B bf16 [8,NE,H] o-values (reused per half)
// ---------------------------------------------------------------------------
extern "C" void kernel_launch(void* const* d_in, const int* in_sizes, int n_in,
                              void* d_out, int out_size, void* d_ws, size_t ws_size,
                              hipStream_t stream)
{
  (void)in_sizes; (void)n_in; (void)out_size; (void)ws_size;
  const float* h0    = (const float*)d_in[0];
  const float* hg    = (const float*)d_in[1];
  const float* x     = (const float*)d_in[2];
  const float* extra = (const float*)d_in[3];
  const int*   dn    = (const int*)d_in[4];
  const int*   idx   = (const int*)d_in[5];
  const float* nnz   = (const float*)d_in[6];
  const float* Wi    = (const float*)d_in[7];
  const float* bi    = (const float*)d_in[8];
  const float* Wh    = (const float*)d_in[9];
  const float* bhn   = (const float*)d_in[10];
  const float* Wq    = (const float*)d_in[11];
  const float* bq    = (const float*)d_in[12];
  const float* Wk    = (const float*)d_in[13];
  const float* bk    = (const float*)d_in[14];
  const float* Wv    = (const float*)d_in[15];
  const float* bv    = (const float*)d_in[16];
  const float* Wo    = (const float*)d_in[17];
  const float* bo    = (const float*)d_in[18];
  const float* W1    = (const float*)d_in[19];
  const float* b1    = (const float*)d_in[20];
  const float* W2    = (const float*)d_in[21];
  const float* b2    = (const float*)d_in[22];
  const float* Wv1   = (const float*)d_in[23];
  const float* bv1   = (const float*)d_in[24];
  (void)nnz;

  float* out = (float*)d_out;
  float* out_hfin  = out;                 // [B,N,H]    4194304
  float* out_hg    = out + 4194304;       // [B,K,DOUT]    1024
  float* out_logit = out + 4195328;       // [T,B,N]     262144
  float* out_value = out + 4457472;       // [T,B]           16

  char* wsb = (char*)d_ws;
  float*          yg     = (float*)wsb;
  int*            cnt    = (int*)(wsb + 16384);
  int*            offs   = (int*)(wsb + 81920);
  int*            cursor = (int*)(wsb + 147584);
  int*            elist  = (int*)(wsb + 213120);
  unsigned short* whTg   = (unsigned short*)(wsb + 409728);
  unsigned short* wT     = (unsigned short*)(wsb + 434304);
  unsigned short* w1Tg   = (unsigned short*)(wsb + 467072);
  unsigned short* hs     = (unsigned short*)(wsb + 524288);
  unsigned short* a_edge = (unsigned short*)(wsb + 34078720);

  hipMemsetAsync(wsb, 0, 81920, stream);      // yg + cnt
  k_prep<<<320, 256, 0, stream>>>(idx, cnt, Wh, whTg, Wq, Wk, Wv, Wo, wT,
                                  W1, w1Tg);
  k_csr_scan<<<1, 256, 0, stream>>>(cnt, offs, cursor);
  k_csr_fill<<<192, 256, 0, stream>>>(idx, cursor, elist);
  k_gru<<<1024, 256, 0, stream>>>(h0, x, dn, whTg, Wi, bi, bhn, hs, out_hfin);
  for (int half = 0; half < 2; ++half) {
    const int tb0 = half * 8;
    k_attn<<<1024, 256, 0, stream>>>(tb0, hs, idx, wT, bq, bk, bv, a_edge);
    k_head<<<2048, 256, 0, stream>>>(tb0, a_edge, offs, elist, wT, bo, extra,
                                     W1, b1, w1Tg, W2, b2, yg, out_logit);
  }
  k_final<<<1, 256, 0, stream>>>(yg, extra, Wv1, bv1, hg, out_value, out_hg);
}

// Round 13
// 288.397 us; speedup vs baseline: 1.0215x; 1.0215x over previous
//
#include <hip/hip_runtime.h>
#include <hip/hip_bf16.h>

#define T_ 4
#define B_ 4
#define N_ 16384
#define KALL_ 4
#define F_ 16384
#define ORD_ 3
#define DIN_ 4
#define H_ 64
#define H3_ 192
#define DE_ 4
#define STR 72   // padded bf16 leading-dim for MFMA A/B LDS tiles (k_head)
#define NE_ 49152  // F*ORD edges

typedef __attribute__((ext_vector_type(8))) short s16x8;
typedef __attribute__((ext_vector_type(4))) float f32x4;
typedef __attribute__((ext_vector_type(2))) float f32x2;
typedef unsigned long long u64;

static __device__ __forceinline__ float b2f(unsigned short u) {
  union { unsigned u; float f; } x; x.u = ((unsigned)u) << 16; return x.f;
}
static __device__ __forceinline__ unsigned short f2b(float f) {
  __hip_bfloat16 h = __float2bfloat16(f);  // RNE
  union { __hip_bfloat16 h; unsigned short u; } x; x.h = h; return x.u;
}
static __device__ __forceinline__ float sigm_fast(float v) {
  return __builtin_amdgcn_rcpf(1.f + __expf(-v));
}
static __device__ __forceinline__ float tanh_fast(float v) {
  float e = __expf(2.f * v);
  return 1.f - 2.f * __builtin_amdgcn_rcpf(e + 1.f);
}

// ---------------------------------------------------------------------------
// Fused prep: CSR count (blocks 0..191) + Wh permute/convert (192..239) +
// attn-weight transpose/convert (240..303) + W1 transpose/convert (304..319).
// ---------------------------------------------------------------------------
__global__ __launch_bounds__(256) void k_prep(
    const int* __restrict__ idx, int* __restrict__ cnt,
    const float* __restrict__ Wh, unsigned short* __restrict__ whTg,
    const float* __restrict__ Wq, const float* __restrict__ Wk,
    const float* __restrict__ Wv, const float* __restrict__ Wo,
    unsigned short* __restrict__ wT,
    const float* __restrict__ W1, unsigned short* __restrict__ w1Tg) {
  const int b = blockIdx.x, tid = threadIdx.x;
  if (b < 192) {
    int e = b * 256 + tid;
    if (e < NE_) atomicAdd(&cnt[idx[e]], 1);
  } else if (b < 240) {
    // whTg[rr*64+k], rr=16*ct+c, ct=g*4+cg holds Wh[k][g*64+4*c+cg]
    int i = (b - 192) * 256 + tid;        // 48*256 = 12288
    int rr = i >> 6, k = i & 63;
    int ct = rr >> 4, c = rr & 15;
    int g = ct >> 2, cg = ct & 3;
    whTg[i] = f2b(Wh[k * H3_ + g * 64 + 4 * c + cg]);
  } else if (b < 304) {
    // wT[m][col][k] so a per-lane B-fragment is one contiguous 16-B load
    int i = (b - 240) * 256 + tid;        // 64*256 = 16384
    int m = i >> 12, col = (i >> 6) & 63, k = i & 63;
    const float* Wm = (m == 0) ? Wq : (m == 1) ? Wk : (m == 2) ? Wv : Wo;
    wT[i] = f2b(Wm[k * 64 + col]);
  } else {
    // w1Tg[col*64+k] = W1[k][col], k<64 (extra rows handled via hEx)
    int i = (b - 304) * 256 + tid;        // 16*256 = 4096
    int col = i >> 6, k = i & 63;
    w1Tg[i] = f2b(W1[k * 64 + col]);
  }
}

__global__ __launch_bounds__(256) void k_csr_scan(
    const int* __restrict__ cnt, int* __restrict__ offs, int* __restrict__ cursor) {
  __shared__ int part[256];
  __shared__ int base[256];
  int t = threadIdx.x;
  int s = 0;
  for (int j = 0; j < 64; ++j) s += cnt[t * 64 + j];
  part[t] = s;
  __syncthreads();
  if (t == 0) {
    int run = 0;
    for (int i = 0; i < 256; ++i) { base[i] = run; run += part[i]; }
  }
  __syncthreads();
  int run = base[t];
  for (int j = 0; j < 64; ++j) {
    offs[t * 64 + j] = run;
    cursor[t * 64 + j] = run;
    run += cnt[t * 64 + j];
  }
  if (t == 255) offs[N_] = run;
}
__global__ __launch_bounds__(256) void k_csr_fill(
    const int* __restrict__ idx, int* __restrict__ cursor, int* __restrict__ elist) {
  int e = blockIdx.x * 256 + threadIdx.x;
  if (e < NE_) {
    int pos = atomicAdd(&cursor[idx[e]], 1);
    elist[pos] = e;
  }
}

// ---------------------------------------------------------------------------
// Kernel 1: GRU v5 (verified R8: VGPR 112, 43 µs). Barrier-free t-loop,
// carry f32 in regs, permuted-column WhT, two cg-halves with sched_barrier
// keeping the halves' register sets apart.
// ---------------------------------------------------------------------------
__global__ __launch_bounds__(256) void k_gru(
    const float* __restrict__ h0,
    const float* __restrict__ x,
    const int* __restrict__ dones,
    const unsigned short* __restrict__ whTg,
    const float* __restrict__ Wi,
    const float* __restrict__ bi,
    const float* __restrict__ bhn,
    unsigned short* __restrict__ hs,     // [T*B,N,H] bf16
    float* __restrict__ hfin)            // [B,N,H] f32
{
  __shared__ __align__(16) short whT[H3_ * 72];    // 27648 B, bf16 B-tiles
  __shared__ __align__(16) short carry[H_ * 72];   // 9216 B, bf16 A-tiles
  __shared__ float wiS[5 * H3_];                   // 3840 B: Wi rows 0..3, bi row 4

  const int tid = threadIdx.x;
  const int lane = tid & 63;
  const int w = tid >> 6;
  const int c15 = lane & 15;
  const int hi4 = lane >> 4;
  const int bid = blockIdx.x;
  const int b = bid >> 8;
  const int nbase = (bid & 255) * 64;
  const int hb = 4 * c15;                 // contiguous h-base of this lane

  // stage whT (pre-converted, permuted): 6 x 16-byte copies per thread
#pragma unroll
  for (int c = 0; c < 6; ++c) {
    int lin = (c * 256 + tid) * 8;        // element index, 8 bf16 per copy
    int row = lin >> 6, col = lin & 63;
    *(s16x8*)&whT[row * 72 + col] = *(const s16x8*)&whTg[lin];
  }
  // stage Wi (f32) + bias row
  for (int i = tid; i < 5 * H3_; i += 256)
    wiS[i] = (i < 4 * H3_) ? Wi[i] : bi[i - 4 * H3_];

  // carry state in registers + bf16 LDS copy (wave-private rows)
  f32x4 cf[4];
#pragma unroll
  for (int r = 0; r < 4; ++r) {
    int row = 16 * w + 4 * hi4 + r;
    cf[r] = *(const f32x4*)&h0[(size_t)(b * N_ + nbase + row) * H_ + hb];
    u64 pk = 0;
#pragma unroll
    for (int e = 0; e < 4; ++e) pk |= (u64)f2b(cf[r][e]) << (16 * e);
    *(u64*)&carry[row * 72 + hb] = pk;
  }

  float bhnr[4];
#pragma unroll
  for (int cg = 0; cg < 4; ++cg) bhnr[cg] = bhn[hb + cg];

  // hoisted dones decode -> bitmask (no runtime-indexed array: rule #20)
  unsigned dmask = 0;
  {
    bool word = true;
#pragma unroll
    for (int i = 0; i < 16; ++i) {
      int v = dones[i];
      if (v != 0 && v != 1 && v != 0x3F800000) word = false;
    }
#pragma unroll
    for (int t = 0; t < T_; ++t) {
      int tb = t * B_ + b;
      bool d = word ? (dones[tb] != 0) : (((const unsigned char*)dones)[tb] != 0);
      if (d) dmask |= (1u << t);
    }
  }

  __syncthreads();   // whT/wiS visible; after this the t-loop is barrier-free

  const int rowA = 16 * w + c15;
#pragma unroll 1
  for (int t = 0; t < T_; ++t) {
    if ((dmask >> t) & 1u) {
#pragma unroll
      for (int r = 0; r < 4; ++r) {
        cf[r] = (f32x4){0.f, 0.f, 0.f, 0.f};
        *(u64*)&carry[(16 * w + 4 * hi4 + r) * 72 + hb] = 0ull;
      }
    }

    // A-fragments for this t (carry rows are wave-private; DS ops in-order)
    s16x8 af0 = *(const s16x8*)&carry[rowA * 72 + hi4 * 8];
    s16x8 af1 = *(const s16x8*)&carry[rowA * 72 + 32 + hi4 * 8];

    // x for all 4 rows, loaded early (independent HBM loads)
    f32x4 xv[4];
#pragma unroll
    for (int r = 0; r < 4; ++r) {
      const int node = nbase + 16 * w + 4 * hi4 + r;
      xv[r] = *(const f32x4*)&x[(size_t)((t * B_ + b) * N_ + node) * DIN_];
    }

    // two cg-halves: hh covers output columns hb+2*hh .. hb+2*hh+1
#pragma unroll
    for (int hh = 0; hh < 2; ++hh) {
      f32x4 acc[6];                       // [g*2+c2], only 24 VGPR live
#pragma unroll
      for (int j = 0; j < 6; ++j) acc[j] = (f32x4){0.f, 0.f, 0.f, 0.f};
#pragma unroll
      for (int j = 0; j < 6; ++j) {
        const int ct = (j >> 1) * 4 + 2 * hh + (j & 1);
        acc[j] = __builtin_amdgcn_mfma_f32_16x16x32_bf16(
            af0, *(const s16x8*)&whT[(16 * ct + c15) * 72 + hi4 * 8], acc[j], 0, 0, 0);
      }
#pragma unroll
      for (int j = 0; j < 6; ++j) {
        const int ct = (j >> 1) * 4 + 2 * hh + (j & 1);
        acc[j] = __builtin_amdgcn_mfma_f32_16x16x32_bf16(
            af1, *(const s16x8*)&whT[(16 * ct + c15) * 72 + 32 + hi4 * 8], acc[j], 0, 0, 0);
      }
      const int hb2 = hb + 2 * hh;
#pragma unroll
      for (int r = 0; r < 4; ++r) {
        f32x2 gi[3];
#pragma unroll
        for (int g = 0; g < 3; ++g) {
          f32x2 s = *(const f32x2*)&wiS[4 * H3_ + g * 64 + hb2];   // bias
#pragma unroll
          for (int kk = 0; kk < 4; ++kk) {
            f32x2 wv = *(const f32x2*)&wiS[kk * H3_ + g * 64 + hb2];
            s += xv[r][kk] * wv;
          }
          gi[g] = s;
        }
#pragma unroll
        for (int c2 = 0; c2 < 2; ++c2) {
          const int cg = 2 * hh + c2;
          float rg = sigm_fast(gi[0][c2] + acc[c2][r]);
          float zg = sigm_fast(gi[1][c2] + acc[2 + c2][r]);
          float ng = tanh_fast(gi[2][c2] + rg * (acc[4 + c2][r] + bhnr[cg]));
          float nc = zg * (cf[r][cg] - ng) + ng;   // (1-z)n + z*c
          cf[r][cg] = nc;
        }
      }
      __builtin_amdgcn_sched_barrier(0);  // keep the two halves' regs apart
    }

    // single store phase per t from cf
#pragma unroll
    for (int r = 0; r < 4; ++r) {
      const int row = 16 * w + 4 * hi4 + r;
      const int node = nbase + row;
      u64 pk = 0;
#pragma unroll
      for (int e = 0; e < 4; ++e) pk |= (u64)f2b(cf[r][e]) << (16 * e);
      *(u64*)&hs[(size_t)((t * B_ + b) * N_ + node) * H_ + hb] = pk;
      *(u64*)&carry[row * 72 + hb] = pk;
      if (t == T_ - 1)
        *(f32x4*)&hfin[(size_t)(b * N_ + node) * H_ + hb] = cf[r];
    }
    // no __syncthreads: carry rows are wave-private, whT/wiS read-only
  }
}

// ---------------------------------------------------------------------------
// Kernel 2 v6 (verified R8, best wall time): 8-slice loop, f32 Q/K LDS, no
// Wo phase (folded into k_head). softmax+PV writes o directly to a_edge.
// ---------------------------------------------------------------------------
__global__ __launch_bounds__(256) void k_attn(
    const int tb0,
    const unsigned short* __restrict__ hs,    // [T*B,N,H] bf16
    const int* __restrict__ indices,
    const unsigned short* __restrict__ wT,    // [4][64][64] bf16
    const float* __restrict__ bq, const float* __restrict__ bk,
    const float* __restrict__ bv,
    unsigned short* __restrict__ a_edge)      // [8,NE,H] bf16 — o values
{
  __shared__ __align__(16) unsigned short bufrag[3072]; // 6144 B, A frags
  __shared__ __align__(16) float qs[48 * 68];           // 13056 B
  __shared__ __align__(16) float ksh[48 * 68];          // 13056 B
  __shared__ __align__(8)  unsigned short vs[48 * 68];  // 6528 B
  __shared__ int idxs[48];

  const int tid = threadIdx.x;
  const int lane = tid & 63;
  const int w = tid >> 6;
  const int c15 = lane & 15;
  const int hi4 = lane >> 4;
  const int bid = blockIdx.x;
  const int col = 16 * w + c15;
  const int swz = (c15 ^ (hi4 << 2));         // swizzled frag-read row

  if (tid < 48) idxs[tid] = indices[bid * 48 + tid];

  // per-wave B fragments: one contiguous 16-B load each from wT
  s16x8 wB[3][2];
#pragma unroll
  for (int m = 0; m < 3; ++m)
#pragma unroll
    for (int ks = 0; ks < 2; ++ks)
      wB[m][ks] = *(const s16x8*)&wT[(m * 64 + col) * 64 + ks * 32 + hi4 * 8];
  const float bq_c = bq[col], bk_c = bk[col], bv_c = bv[col];
  __syncthreads();                            // idxs ready

  // gather geometry: thread covers rows grow, grow+16, grow+32 at group gg
  const int grow = tid >> 4, gg = tid & 15;
  const int gks = gg >> 3, gh5 = (gg >> 1) & 3, gj = (gg & 1) * 4;
  size_t goff[3];
  int boff[3];
#pragma unroll
  for (int k = 0; k < 3; ++k) {
    goff[k] = (size_t)idxs[grow + k * 16] * H_ + gg * 4;
    int cr2 = grow ^ (gh5 << 2);              // rt == k, cr == grow
    boff[k] = ((k * 2 + gks) << 9) + ((gh5 * 16 + cr2) << 3) + gj;
  }

  // prefetch slice 0
  u64 pf[3];
  {
    const unsigned short* hp = hs + (size_t)tb0 * (N_ * H_);
#pragma unroll
    for (int k = 0; k < 3; ++k) pf[k] = *(const u64*)&hp[goff[k]];
  }

  for (int it = 0; it < 8; ++it) {
#pragma unroll
    for (int k = 0; k < 3; ++k) *(u64*)&bufrag[boff[k]] = pf[k];
    __syncthreads();                          // B1: frags staged

    // ---- QKV projections: q,k stored f32 (no converts), v bf16 ----
    s16x8 afr[3][2];
#pragma unroll
    for (int rt = 0; rt < 3; ++rt)
#pragma unroll
      for (int ks = 0; ks < 2; ++ks)
        afr[rt][ks] = *(const s16x8*)&bufrag[((rt * 2 + ks) << 9) + ((hi4 * 16 + swz) << 3)];
#pragma unroll
    for (int rt = 0; rt < 3; ++rt) {
      f32x4 aq = (f32x4){0.f, 0.f, 0.f, 0.f};
      aq = __builtin_amdgcn_mfma_f32_16x16x32_bf16(afr[rt][0], wB[0][0], aq, 0, 0, 0);
      aq = __builtin_amdgcn_mfma_f32_16x16x32_bf16(afr[rt][1], wB[0][1], aq, 0, 0, 0);
#pragma unroll
      for (int r = 0; r < 4; ++r)
        qs[(16 * rt + hi4 * 4 + r) * 68 + col] = (aq[r] + bq_c) * 0.25f;
    }
#pragma unroll
    for (int rt = 0; rt < 3; ++rt) {
      f32x4 ak = (f32x4){0.f, 0.f, 0.f, 0.f};
      ak = __builtin_amdgcn_mfma_f32_16x16x32_bf16(afr[rt][0], wB[1][0], ak, 0, 0, 0);
      ak = __builtin_amdgcn_mfma_f32_16x16x32_bf16(afr[rt][1], wB[1][1], ak, 0, 0, 0);
#pragma unroll
      for (int r = 0; r < 4; ++r)
        ksh[(16 * rt + hi4 * 4 + r) * 68 + col] = ak[r] + bk_c;
    }
#pragma unroll
    for (int rt = 0; rt < 3; ++rt) {
      f32x4 av = (f32x4){0.f, 0.f, 0.f, 0.f};
      av = __builtin_amdgcn_mfma_f32_16x16x32_bf16(afr[rt][0], wB[2][0], av, 0, 0, 0);
      av = __builtin_amdgcn_mfma_f32_16x16x32_bf16(afr[rt][1], wB[2][1], av, 0, 0, 0);
#pragma unroll
      for (int r = 0; r < 4; ++r)
        vs[(16 * rt + hi4 * 4 + r) * 68 + col] = f2b(av[r] + bv_c);
    }
    // prefetch next slice (flat loads off scalar base)
    if (it < 7) {
      const unsigned short* hp = hs + (size_t)(tb0 + it + 1) * (N_ * H_);
#pragma unroll
      for (int k = 0; k < 3; ++k) pf[k] = *(const u64*)&hp[goff[k]];
    }
    __syncthreads();                          // B2: qkv ready

    // ---- softmax + PV: thread = (f, head, dq); o -> global directly ----
    {
      int f = tid >> 4, head = (tid >> 2) & 3, dq = tid & 3;
      int colb = head * 16 + dq * 4;
      f32x4 qv[3], kv[3];
      float vv[3][4];
#pragma unroll
      for (int qi = 0; qi < 3; ++qi) {
        int base = (3 * f + qi) * 68 + colb;
        qv[qi] = *(const f32x4*)&qs[base];
        kv[qi] = *(const f32x4*)&ksh[base];
        u64 uv = *(const u64*)&vs[base];
#pragma unroll
        for (int e = 0; e < 4; ++e)
          vv[qi][e] = b2f((unsigned short)(uv >> (16 * e)));
      }
      float s[3][3];
#pragma unroll
      for (int qi = 0; qi < 3; ++qi)
#pragma unroll
        for (int ki = 0; ki < 3; ++ki) {
          float a = qv[qi][0] * kv[ki][0] + qv[qi][1] * kv[ki][1]
                  + qv[qi][2] * kv[ki][2] + qv[qi][3] * kv[ki][3];
          a += __shfl_xor(a, 1, 64);
          a += __shfl_xor(a, 2, 64);
          s[qi][ki] = a;
        }
      const size_t abase = (size_t)it * NE_ + (size_t)bid * 48;
#pragma unroll
      for (int qi = 0; qi < 3; ++qi) {
        float mx = fmaxf(s[qi][0], fmaxf(s[qi][1], s[qi][2]));
        float e0 = __expf(s[qi][0] - mx), e1 = __expf(s[qi][1] - mx), e2 = __expf(s[qi][2] - mx);
        float inv = 1.f / (e0 + e1 + e2);
        e0 *= inv; e1 *= inv; e2 *= inv;
        int row = 3 * f + qi;
        u64 pack = 0;
#pragma unroll
        for (int e = 0; e < 4; ++e) {
          float o = e0 * vv[0][e] + e1 * vv[1][e] + e2 * vv[2][e];
          pack |= (u64)f2b(o) << (16 * e);
        }
        *(u64*)&a_edge[(abase + row) * H_ + colb] = pack;
      }
    }
    __syncthreads();                          // B3: qkv/bufrag reusable
  }
}

// ---------------------------------------------------------------------------
// Kernel 3 v4 (verified R8): u64 gather, rcp, pre-converted W1 staging,
// Wo absorbed as extra MFMA GEMM.
// ---------------------------------------------------------------------------
__global__ __launch_bounds__(256) void k_head(
    const int tb0,
    const unsigned short* __restrict__ a_edge, // [8,NE,H] bf16 — o values
    const int* __restrict__ offs, const int* __restrict__ elist,
    const unsigned short* __restrict__ wT,     // [4][64][64]; m=3 is Wo
    const float* __restrict__ bo,
    const float* __restrict__ extra,
    const float* __restrict__ W1, const float* __restrict__ b1,
    const unsigned short* __restrict__ w1Tg,   // [64][64] bf16 transposed
    const float* __restrict__ W2, const float* __restrict__ b2,
    float* __restrict__ yg,                    // [T*B,KALL,H] f32, pre-zeroed
    float* __restrict__ logit)                 // [T,B,N] f32
{
  __shared__ __align__(16) short w1T[64 * STR];
  __shared__ __align__(16) short arow[64 * STR];
  __shared__ int offsS[65];
  __shared__ int eidS[512];
  __shared__ float hEx[64];
  __shared__ float w2s[64];
  __shared__ float hasES[64];
  __shared__ float red[4][64];

  const int tid = threadIdx.x;
  const int lane = tid & 63;
  const int w = tid >> 6;
  const int c15 = lane & 15;
  const int hi4 = lane >> 4;
  const int bid = blockIdx.x;
  const int ls = bid >> 8;             // local slice 0..7
  const int tb = tb0 + ls;
  const int nbase = (bid & 255) * 64;
  const int kall = nbase >> 12;

  // stage w1T from pre-converted w1Tg: 2 x 16-B copies per thread
#pragma unroll
  for (int c = 0; c < 2; ++c) {
    int lin = (c * 256 + tid) * 8;
    int row = lin >> 6, col = lin & 63;
    *(s16x8*)&w1T[row * STR + col] = *(const s16x8*)&w1Tg[lin];
  }
  if (tid < 65) offsS[tid] = offs[nbase + tid];
  if (tid < 64) {
    float s = b1[tid];
#pragma unroll
    for (int e = 0; e < 4; ++e)
      s += extra[(tb * KALL_ + kall) * DE_ + e] * W1[(64 + e) * 64 + tid];
    hEx[tid] = s;
    w2s[tid] = W2[tid];
  }
  // Wo B-fragments + bias in registers (coalesced 16-B loads from wT)
  s16x8 wo_b[2][4];
  float boc[4];
#pragma unroll
  for (int ct = 0; ct < 4; ++ct) {
    boc[ct] = bo[16 * ct + c15];
#pragma unroll
    for (int ks = 0; ks < 2; ++ks)
      wo_b[ks][ct] = *(const s16x8*)&wT[(192 + 16 * ct + c15) * 64 + ks * 32 + hi4 * 8];
  }
  // edge-range staging
  const int ebeg = offs[nbase];
  const int ecnt = offs[nbase + 64] - ebeg;
  const bool fast = (ecnt <= 512);
  if (tid == 0) eidS[0] = 0;           // safe dup slot even when ecnt == 0
  if (fast) {
    for (int j = tid; j < ecnt; j += 256) eidS[j] = elist[ebeg + j];
  }
  __syncthreads();

  const size_t ebase = (size_t)ls * NE_;
  if (fast) {
    const int cg = tid & 15;
#pragma unroll
    for (int ku = 0; ku < 4; ++ku) {
      const int r = ku * 16 + (tid >> 4);
      const int beg = offsS[r] - ebeg, end = offsS[r + 1] - ebeg;
      const int cnt = end - beg;
      const float inv = __builtin_amdgcn_rcpf(fmaxf((float)cnt, 1.f));
      f32x4 s = (f32x4){0.f, 0.f, 0.f, 0.f};
#pragma unroll
      for (int u = 0; u < 8; ++u) {
        int p = beg + u;
        bool valid = p < end;
        int pc = valid ? p : 0;        // dup -> eidS[0] row, L1-hot
        u64 v = *(const u64*)&a_edge[(ebase + eidS[pc]) * H_ + cg * 4];
        if (!valid) v = 0;             // 2 cndmasks; b2f(0)=0
        s[0] += b2f((unsigned short)v);
        s[1] += b2f((unsigned short)(v >> 16));
        s[2] += b2f((unsigned short)(v >> 32));
        s[3] += b2f((unsigned short)(v >> 48));
      }
      for (int p = beg + 8; p < end; ++p) {        // rare tail (cnt > 8)
        u64 v = *(const u64*)&a_edge[(ebase + eidS[p]) * H_ + cg * 4];
        s[0] += b2f((unsigned short)v);
        s[1] += b2f((unsigned short)(v >> 16));
        s[2] += b2f((unsigned short)(v >> 32));
        s[3] += b2f((unsigned short)(v >> 48));
      }
      u64 pk = 0;
#pragma unroll
      for (int e = 0; e < 4; ++e) pk |= (u64)f2b(s[e] * inv) << (16 * e);
      *(u64*)&arow[r * STR + cg * 4] = pk;
      if (cg == 0) hasES[r] = (cnt > 0) ? 1.f : 0.f;
    }
  } else {
    // fallback: direct-global dynamic loop (never taken for this input size)
    for (int r = w; r < 64; r += 4) {
      const int beg = offsS[r], end = offsS[r + 1];
      float s = 0.f;
      for (int p = beg; p < end; ++p)
        s += b2f(a_edge[(ebase + elist[p]) * H_ + lane]);
      float val = s / fmaxf((float)(end - beg), 1.f);
      arow[r * STR + lane] = (short)f2b(val);
      if (lane == 0) hasES[r] = (end > beg) ? 1.f : 0.f;
    }
  }
  __syncthreads();

  // ---- Wo GEMM: o-mean -> y; overwrite arow in place (wave-private rows,
  // same-wave DS ordering makes reads-before-writes safe) ----
  f32x4 acco[4];
#pragma unroll
  for (int ct = 0; ct < 4; ++ct) acco[ct] = (f32x4){0.f, 0.f, 0.f, 0.f};
#pragma unroll
  for (int ks = 0; ks < 2; ++ks) {
    int kb = ks * 32 + hi4 * 8;
    s16x8 af = *(const s16x8*)&arow[(16 * w + c15) * STR + kb];
#pragma unroll
    for (int ct = 0; ct < 4; ++ct)
      acco[ct] = __builtin_amdgcn_mfma_f32_16x16x32_bf16(af, wo_b[ks][ct], acco[ct], 0, 0, 0);
  }
  float sumy[4] = {0.f, 0.f, 0.f, 0.f};
#pragma unroll
  for (int r = 0; r < 4; ++r) {
    const int rowr = 16 * w + hi4 * 4 + r;
    const float hase = hasES[rowr];
#pragma unroll
    for (int ct = 0; ct < 4; ++ct) {
      float y = acco[ct][r] + hase * boc[ct];
      arow[rowr * STR + 16 * ct + c15] = (short)f2b(y);
      sumy[ct] += y;
    }
  }
#pragma unroll
  for (int ct = 0; ct < 4; ++ct) {
    sumy[ct] += __shfl_xor(sumy[ct], 16, 64);
    sumy[ct] += __shfl_xor(sumy[ct], 32, 64);
  }
  if (hi4 == 0) {
#pragma unroll
    for (int ct = 0; ct < 4; ++ct) red[w][16 * ct + c15] = sumy[ct];
  }

  // ---- W1 GEMM (reads own wave's arow_y rows; no barrier needed) ----
  f32x4 acc[4];
#pragma unroll
  for (int ct = 0; ct < 4; ++ct) acc[ct] = (f32x4){0.f, 0.f, 0.f, 0.f};
#pragma unroll
  for (int ks = 0; ks < 2; ++ks) {
    int kb = ks * 32 + hi4 * 8;
    s16x8 af = *(const s16x8*)&arow[(16 * w + c15) * STR + kb];
#pragma unroll
    for (int ct = 0; ct < 4; ++ct) {
      s16x8 bfr = *(const s16x8*)&w1T[(16 * ct + c15) * STR + kb];
      acc[ct] = __builtin_amdgcn_mfma_f32_16x16x32_bf16(af, bfr, acc[ct], 0, 0, 0);
    }
  }
  const float b2v = b2[0];
#pragma unroll
  for (int r = 0; r < 4; ++r) {
    float s = 0.f;
#pragma unroll
    for (int ct = 0; ct < 4; ++ct) {
      int colc = 16 * ct + c15;
      s += fmaxf(acc[ct][r] + hEx[colc], 0.f) * w2s[colc];
    }
    s += __shfl_xor(s, 1, 64);
    s += __shfl_xor(s, 2, 64);
    s += __shfl_xor(s, 4, 64);
    s += __shfl_xor(s, 8, 64);
    if (c15 == 0)
      logit[tb * N_ + nbase + 16 * w + hi4 * 4 + r] = s + b2v;
  }
  __syncthreads();
  if (tid < 64) {
    float sv = red[0][tid] + red[1][tid] + red[2][tid] + red[3][tid];
    atomicAdd(&yg[(tb * KALL_ + kall) * H_ + tid], sv);
  }
}

// ---------------------------------------------------------------------------
// Kernel 4: value head + h_global passthrough (f32)
// ---------------------------------------------------------------------------
__global__ __launch_bounds__(256) void k_final(
    const float* __restrict__ yg,
    const float* __restrict__ extra,
    const float* __restrict__ Wv1, const float* __restrict__ bv1,
    const float* __restrict__ hg_in,
    float* __restrict__ value_out,
    float* __restrict__ hg_out)
{
  const int tid = threadIdx.x;
  if (tid < 16) {
    const float bv = bv1[0];
    float v = 0.f;
    for (int kall = 0; kall < 4; ++kall) {
      float s = bv;
      for (int hh = 0; hh < 64; ++hh)
        s += (yg[(tid * KALL_ + kall) * H_ + hh] * (1.f / 4096.f)) * Wv1[hh];
      for (int e = 0; e < 4; ++e)
        s += extra[(tid * KALL_ + kall) * DE_ + e] * Wv1[64 + e];
      v += s;
    }
    value_out[tid] = v;
  }
  for (int i = tid; i < 1024; i += 256) hg_out[i] = hg_in[i];
}

// ---------------------------------------------------------------------------
// Workspace layout (84.4 MB, proven safe):
//   yg     @ 0        : 16,384 B    f32 [T*B,KALL,H]
//   cnt    @ 16384    : 65,536 B    int [N]
//   offs   @ 81920    : 65,540 B    int [N+1]
//   cursor @ 147584   : 65,536 B    int [N]
//   elist  @ 213120   : 196,608 B   int [NE]
//   whTg   @ 409728   : 24,576 B    bf16 [192][64] permuted WhT
//   wT     @ 434304   : 32,768 B    bf16 [4][64][64] transposed Wq/Wk/Wv/Wo
//   w1Tg   @ 467072   : 8,192 B     bf16 [64][64] transposed W1
//   hs     @ 524288   : 33,554,432 B bf16 [T*B,N,H]
//   a_edge @ 34078720 : 50,331,648 B bf16 [8,NE,H] o-values (reused per half)
// ---------------------------------------------------------------------------
extern "C" void kernel_launch(void* const* d_in, const int* in_sizes, int n_in,
                              void* d_out, int out_size, void* d_ws, size_t ws_size,
                              hipStream_t stream)
{
  (void)in_sizes; (void)n_in; (void)out_size; (void)ws_size;
  const float* h0    = (const float*)d_in[0];
  const float* hg    = (const float*)d_in[1];
  const float* x     = (const float*)d_in[2];
  const float* extra = (const float*)d_in[3];
  const int*   dn    = (const int*)d_in[4];
  const int*   idx   = (const int*)d_in[5];
  const float* nnz   = (const float*)d_in[6];
  const float* Wi    = (const float*)d_in[7];
  const float* bi    = (const float*)d_in[8];
  const float* Wh    = (const float*)d_in[9];
  const float* bhn   = (const float*)d_in[10];
  const float* Wq    = (const float*)d_in[11];
  const float* bq    = (const float*)d_in[12];
  const float* Wk    = (const float*)d_in[13];
  const float* bk    = (const float*)d_in[14];
  const float* Wv    = (const float*)d_in[15];
  const float* bv    = (const float*)d_in[16];
  const float* Wo    = (const float*)d_in[17];
  const float* bo    = (const float*)d_in[18];
  const float* W1    = (const float*)d_in[19];
  const float* b1    = (const float*)d_in[20];
  const float* W2    = (const float*)d_in[21];
  const float* b2    = (const float*)d_in[22];
  const float* Wv1   = (const float*)d_in[23];
  const float* bv1   = (const float*)d_in[24];
  (void)nnz;

  float* out = (float*)d_out;
  float* out_hfin  = out;                 // [B,N,H]    4194304
  float* out_hg    = out + 4194304;       // [B,K,DOUT]    1024
  float* out_logit = out + 4195328;       // [T,B,N]     262144
  float* out_value = out + 4457472;       // [T,B]           16

  char* wsb = (char*)d_ws;
  float*          yg     = (float*)wsb;
  int*            cnt    = (int*)(wsb + 16384);
  int*            offs   = (int*)(wsb + 81920);
  int*            cursor = (int*)(wsb + 147584);
  int*            elist  = (int*)(wsb + 213120);
  unsigned short* whTg   = (unsigned short*)(wsb + 409728);
  unsigned short* wT     = (unsigned short*)(wsb + 434304);
  unsigned short* w1Tg   = (unsigned short*)(wsb + 467072);
  unsigned short* hs     = (unsigned short*)(wsb + 524288);
  unsigned short* a_edge = (unsigned short*)(wsb + 34078720);

  hipMemsetAsync(wsb, 0, 81920, stream);      // yg + cnt
  k_prep<<<320, 256, 0, stream>>>(idx, cnt, Wh, whTg, Wq, Wk, Wv, Wo, wT,
                                  W1, w1Tg);
  k_csr_scan<<<1, 256, 0, stream>>>(cnt, offs, cursor);
  k_csr_fill<<<192, 256, 0, stream>>>(idx, cursor, elist);
  k_gru<<<1024, 256, 0, stream>>>(h0, x, dn, whTg, Wi, bi, bhn, hs, out_hfin);
  for (int half = 0; half < 2; ++half) {
    const int tb0 = half * 8;
    k_attn<<<1024, 256, 0, stream>>>(tb0, hs, idx, wT, bq, bk, bv, a_edge);
    k_head<<<2048, 256, 0, stream>>>(tb0, a_edge, offs, elist, wT, bo, extra,
                                     W1, b1, w1Tg, W2, b2, yg, out_logit);
  }
  k_final<<<1, 256, 0, stream>>>(yg, extra, Wv1, bv1, hg, out_value, out_hg);
}

// Round 14
// 276.862 us; speedup vs baseline: 1.0641x; 1.0417x over previous
//
#include <hip/hip_runtime.h>
#include <hip/hip_bf16.h>

#define T_ 4
#define B_ 4
#define N_ 16384
#define KALL_ 4
#define F_ 16384
#define ORD_ 3
#define DIN_ 4
#define H_ 64
#define H3_ 192
#define DE_ 4
#define STR 72   // padded bf16 leading-dim for MFMA A/B LDS tiles (k_head)
#define NE_ 49152  // F*ORD edges

typedef __attribute__((ext_vector_type(8))) short s16x8;
typedef __attribute__((ext_vector_type(4))) float f32x4;
typedef __attribute__((ext_vector_type(2))) float f32x2;
typedef unsigned long long u64;

static __device__ __forceinline__ float b2f(unsigned short u) {
  union { unsigned u; float f; } x; x.u = ((unsigned)u) << 16; return x.f;
}
static __device__ __forceinline__ unsigned short f2b(float f) {
  __hip_bfloat16 h = __float2bfloat16(f);  // RNE
  union { __hip_bfloat16 h; unsigned short u; } x; x.h = h; return x.u;
}
static __device__ __forceinline__ float sigm_fast(float v) {
  return __builtin_amdgcn_rcpf(1.f + __expf(-v));
}
static __device__ __forceinline__ float tanh_fast(float v) {
  float e = __expf(2.f * v);
  return 1.f - 2.f * __builtin_amdgcn_rcpf(e + 1.f);
}

// ---------------------------------------------------------------------------
// Fused prep: CSR count (blocks 0..191) + Wh permute/convert (192..239) +
// attn-weight transpose/convert (240..303) + W1 transpose/convert (304..319).
// ---------------------------------------------------------------------------
__global__ __launch_bounds__(256) void k_prep(
    const int* __restrict__ idx, int* __restrict__ cnt,
    const float* __restrict__ Wh, unsigned short* __restrict__ whTg,
    const float* __restrict__ Wq, const float* __restrict__ Wk,
    const float* __restrict__ Wv, const float* __restrict__ Wo,
    unsigned short* __restrict__ wT,
    const float* __restrict__ W1, unsigned short* __restrict__ w1Tg) {
  const int b = blockIdx.x, tid = threadIdx.x;
  if (b < 192) {
    int e = b * 256 + tid;
    if (e < NE_) atomicAdd(&cnt[idx[e]], 1);
  } else if (b < 240) {
    // whTg[rr*64+k], rr=16*ct+c, ct=g*4+cg holds Wh[k][g*64+4*c+cg]
    int i = (b - 192) * 256 + tid;        // 48*256 = 12288
    int rr = i >> 6, k = i & 63;
    int ct = rr >> 4, c = rr & 15;
    int g = ct >> 2, cg = ct & 3;
    whTg[i] = f2b(Wh[k * H3_ + g * 64 + 4 * c + cg]);
  } else if (b < 304) {
    // wT[m][col][k] so a per-lane B-fragment is one contiguous 16-B load
    int i = (b - 240) * 256 + tid;        // 64*256 = 16384
    int m = i >> 12, col = (i >> 6) & 63, k = i & 63;
    const float* Wm = (m == 0) ? Wq : (m == 1) ? Wk : (m == 2) ? Wv : Wo;
    wT[i] = f2b(Wm[k * 64 + col]);
  } else {
    // w1Tg[col*64+k] = W1[k][col], k<64 (extra rows handled via hEx)
    int i = (b - 304) * 256 + tid;        // 16*256 = 4096
    int col = i >> 6, k = i & 63;
    w1Tg[i] = f2b(W1[k * 64 + col]);
  }
}

__global__ __launch_bounds__(256) void k_csr_scan(
    const int* __restrict__ cnt, int* __restrict__ offs, int* __restrict__ cursor) {
  __shared__ int part[256];
  __shared__ int base[256];
  int t = threadIdx.x;
  int s = 0;
  for (int j = 0; j < 64; ++j) s += cnt[t * 64 + j];
  part[t] = s;
  __syncthreads();
  if (t == 0) {
    int run = 0;
    for (int i = 0; i < 256; ++i) { base[i] = run; run += part[i]; }
  }
  __syncthreads();
  int run = base[t];
  for (int j = 0; j < 64; ++j) {
    offs[t * 64 + j] = run;
    cursor[t * 64 + j] = run;
    run += cnt[t * 64 + j];
  }
  if (t == 255) offs[N_] = run;
}
__global__ __launch_bounds__(256) void k_csr_fill(
    const int* __restrict__ idx, int* __restrict__ cursor, int* __restrict__ elist) {
  int e = blockIdx.x * 256 + threadIdx.x;
  if (e < NE_) {
    int pos = atomicAdd(&cursor[idx[e]], 1);
    elist[pos] = e;
  }
}

// ---------------------------------------------------------------------------
// Kernel 1: GRU v7 = R8's verified v5 re-partitioned to 512-thread blocks
// (128 nodes each, 8 waves x 16 rows). whT (27.6 KB) amortized over 8 waves;
// VGPR 112 -> 4 waves/SIMD -> exactly 2 blocks/CU -> grid 512 = ONE
// residency round (R13 counters: 1024 blocks at 3/CU = 2 rounds, round 2
// only 1/3 full). Per-wave code identical to v5.
// ---------------------------------------------------------------------------
__global__ __launch_bounds__(512) void k_gru(
    const float* __restrict__ h0,
    const float* __restrict__ x,
    const int* __restrict__ dones,
    const unsigned short* __restrict__ whTg,
    const float* __restrict__ Wi,
    const float* __restrict__ bi,
    const float* __restrict__ bhn,
    unsigned short* __restrict__ hs,     // [T*B,N,H] bf16
    float* __restrict__ hfin)            // [B,N,H] f32
{
  __shared__ __align__(16) short whT[H3_ * 72];    // 27648 B, bf16 B-tiles
  __shared__ __align__(16) short carry[128 * 72];  // 18432 B, bf16 A-tiles
  __shared__ float wiS[5 * H3_];                   // 3840 B: Wi rows 0..3, bi row 4

  const int tid = threadIdx.x;
  const int lane = tid & 63;
  const int w = tid >> 6;                 // 0..7
  const int c15 = lane & 15;
  const int hi4 = lane >> 4;
  const int bid = blockIdx.x;             // 512 = 4 b x 128 chunks
  const int b = bid >> 7;
  const int nbase = (bid & 127) * 128;
  const int hb = 4 * c15;                 // contiguous h-base of this lane

  // stage whT (pre-converted, permuted): 3 x 16-byte copies per thread
#pragma unroll
  for (int c = 0; c < 3; ++c) {
    int lin = (c * 512 + tid) * 8;        // element index, 8 bf16 per copy
    int row = lin >> 6, col = lin & 63;
    *(s16x8*)&whT[row * 72 + col] = *(const s16x8*)&whTg[lin];
  }
  // stage Wi (f32) + bias row
  for (int i = tid; i < 5 * H3_; i += 512)
    wiS[i] = (i < 4 * H3_) ? Wi[i] : bi[i - 4 * H3_];

  // carry state in registers + bf16 LDS copy (wave-private rows)
  f32x4 cf[4];
#pragma unroll
  for (int r = 0; r < 4; ++r) {
    int row = 16 * w + 4 * hi4 + r;
    cf[r] = *(const f32x4*)&h0[(size_t)(b * N_ + nbase + row) * H_ + hb];
    u64 pk = 0;
#pragma unroll
    for (int e = 0; e < 4; ++e) pk |= (u64)f2b(cf[r][e]) << (16 * e);
    *(u64*)&carry[row * 72 + hb] = pk;
  }

  float bhnr[4];
#pragma unroll
  for (int cg = 0; cg < 4; ++cg) bhnr[cg] = bhn[hb + cg];

  // hoisted dones decode -> bitmask (no runtime-indexed array: rule #20)
  unsigned dmask = 0;
  {
    bool word = true;
#pragma unroll
    for (int i = 0; i < 16; ++i) {
      int v = dones[i];
      if (v != 0 && v != 1 && v != 0x3F800000) word = false;
    }
#pragma unroll
    for (int t = 0; t < T_; ++t) {
      int tb = t * B_ + b;
      bool d = word ? (dones[tb] != 0) : (((const unsigned char*)dones)[tb] != 0);
      if (d) dmask |= (1u << t);
    }
  }

  __syncthreads();   // whT/wiS visible; after this the t-loop is barrier-free

  const int rowA = 16 * w + c15;
#pragma unroll 1
  for (int t = 0; t < T_; ++t) {
    if ((dmask >> t) & 1u) {
#pragma unroll
      for (int r = 0; r < 4; ++r) {
        cf[r] = (f32x4){0.f, 0.f, 0.f, 0.f};
        *(u64*)&carry[(16 * w + 4 * hi4 + r) * 72 + hb] = 0ull;
      }
    }

    // A-fragments for this t (carry rows are wave-private; DS ops in-order)
    s16x8 af0 = *(const s16x8*)&carry[rowA * 72 + hi4 * 8];
    s16x8 af1 = *(const s16x8*)&carry[rowA * 72 + 32 + hi4 * 8];

    // x for all 4 rows, loaded early (independent HBM loads)
    f32x4 xv[4];
#pragma unroll
    for (int r = 0; r < 4; ++r) {
      const int node = nbase + 16 * w + 4 * hi4 + r;
      xv[r] = *(const f32x4*)&x[(size_t)((t * B_ + b) * N_ + node) * DIN_];
    }

    // two cg-halves: hh covers output columns hb+2*hh .. hb+2*hh+1
#pragma unroll
    for (int hh = 0; hh < 2; ++hh) {
      f32x4 acc[6];                       // [g*2+c2], only 24 VGPR live
#pragma unroll
      for (int j = 0; j < 6; ++j) acc[j] = (f32x4){0.f, 0.f, 0.f, 0.f};
#pragma unroll
      for (int j = 0; j < 6; ++j) {
        const int ct = (j >> 1) * 4 + 2 * hh + (j & 1);
        acc[j] = __builtin_amdgcn_mfma_f32_16x16x32_bf16(
            af0, *(const s16x8*)&whT[(16 * ct + c15) * 72 + hi4 * 8], acc[j], 0, 0, 0);
      }
#pragma unroll
      for (int j = 0; j < 6; ++j) {
        const int ct = (j >> 1) * 4 + 2 * hh + (j & 1);
        acc[j] = __builtin_amdgcn_mfma_f32_16x16x32_bf16(
            af1, *(const s16x8*)&whT[(16 * ct + c15) * 72 + 32 + hi4 * 8], acc[j], 0, 0, 0);
      }
      const int hb2 = hb + 2 * hh;
#pragma unroll
      for (int r = 0; r < 4; ++r) {
        f32x2 gi[3];
#pragma unroll
        for (int g = 0; g < 3; ++g) {
          f32x2 s = *(const f32x2*)&wiS[4 * H3_ + g * 64 + hb2];   // bias
#pragma unroll
          for (int kk = 0; kk < 4; ++kk) {
            f32x2 wv = *(const f32x2*)&wiS[kk * H3_ + g * 64 + hb2];
            s += xv[r][kk] * wv;
          }
          gi[g] = s;
        }
#pragma unroll
        for (int c2 = 0; c2 < 2; ++c2) {
          const int cg = 2 * hh + c2;
          float rg = sigm_fast(gi[0][c2] + acc[c2][r]);
          float zg = sigm_fast(gi[1][c2] + acc[2 + c2][r]);
          float ng = tanh_fast(gi[2][c2] + rg * (acc[4 + c2][r] + bhnr[cg]));
          float nc = zg * (cf[r][cg] - ng) + ng;   // (1-z)n + z*c
          cf[r][cg] = nc;
        }
      }
      __builtin_amdgcn_sched_barrier(0);  // keep the two halves' regs apart
    }

    // single store phase per t from cf
#pragma unroll
    for (int r = 0; r < 4; ++r) {
      const int row = 16 * w + 4 * hi4 + r;
      const int node = nbase + row;
      u64 pk = 0;
#pragma unroll
      for (int e = 0; e < 4; ++e) pk |= (u64)f2b(cf[r][e]) << (16 * e);
      *(u64*)&hs[(size_t)((t * B_ + b) * N_ + node) * H_ + hb] = pk;
      *(u64*)&carry[row * 72 + hb] = pk;
      if (t == T_ - 1)
        *(f32x4*)&hfin[(size_t)(b * N_ + node) * H_ + hb] = cf[r];
    }
    // no __syncthreads: carry rows are wave-private, whT/wiS read-only
  }
}

// ---------------------------------------------------------------------------
// Kernel 2 v6m: R8's verified attn, halves MERGED — one launch loops all 16
// (t,b) slices (weights/idxs/geometry setup amortized 2x, one launch less).
// a_edge is [16,NE,H]. Everything inside the loop byte-identical to R8.
// ---------------------------------------------------------------------------
__global__ __launch_bounds__(256) void k_attn(
    const unsigned short* __restrict__ hs,    // [T*B,N,H] bf16
    const int* __restrict__ indices,
    const unsigned short* __restrict__ wT,    // [4][64][64] bf16
    const float* __restrict__ bq, const float* __restrict__ bk,
    const float* __restrict__ bv,
    unsigned short* __restrict__ a_edge)      // [16,NE,H] bf16 — o values
{
  __shared__ __align__(16) unsigned short bufrag[3072]; // 6144 B, A frags
  __shared__ __align__(16) float qs[48 * 68];           // 13056 B
  __shared__ __align__(16) float ksh[48 * 68];          // 13056 B
  __shared__ __align__(8)  unsigned short vs[48 * 68];  // 6528 B
  __shared__ int idxs[48];

  const int tid = threadIdx.x;
  const int lane = tid & 63;
  const int w = tid >> 6;
  const int c15 = lane & 15;
  const int hi4 = lane >> 4;
  const int bid = blockIdx.x;
  const int col = 16 * w + c15;
  const int swz = (c15 ^ (hi4 << 2));         // swizzled frag-read row

  if (tid < 48) idxs[tid] = indices[bid * 48 + tid];

  // per-wave B fragments: one contiguous 16-B load each from wT
  s16x8 wB[3][2];
#pragma unroll
  for (int m = 0; m < 3; ++m)
#pragma unroll
    for (int ks = 0; ks < 2; ++ks)
      wB[m][ks] = *(const s16x8*)&wT[(m * 64 + col) * 64 + ks * 32 + hi4 * 8];
  const float bq_c = bq[col], bk_c = bk[col], bv_c = bv[col];
  __syncthreads();                            // idxs ready

  // gather geometry: thread covers rows grow, grow+16, grow+32 at group gg
  const int grow = tid >> 4, gg = tid & 15;
  const int gks = gg >> 3, gh5 = (gg >> 1) & 3, gj = (gg & 1) * 4;
  size_t goff[3];
  int boff[3];
#pragma unroll
  for (int k = 0; k < 3; ++k) {
    goff[k] = (size_t)idxs[grow + k * 16] * H_ + gg * 4;
    int cr2 = grow ^ (gh5 << 2);              // rt == k, cr == grow
    boff[k] = ((k * 2 + gks) << 9) + ((gh5 * 16 + cr2) << 3) + gj;
  }

  // prefetch slice 0
  u64 pf[3];
#pragma unroll
  for (int k = 0; k < 3; ++k) pf[k] = *(const u64*)&hs[goff[k]];

  for (int it = 0; it < 16; ++it) {
#pragma unroll
    for (int k = 0; k < 3; ++k) *(u64*)&bufrag[boff[k]] = pf[k];
    __syncthreads();                          // B1: frags staged

    // ---- QKV projections: q,k stored f32 (no converts), v bf16 ----
    s16x8 afr[3][2];
#pragma unroll
    for (int rt = 0; rt < 3; ++rt)
#pragma unroll
      for (int ks = 0; ks < 2; ++ks)
        afr[rt][ks] = *(const s16x8*)&bufrag[((rt * 2 + ks) << 9) + ((hi4 * 16 + swz) << 3)];
#pragma unroll
    for (int rt = 0; rt < 3; ++rt) {
      f32x4 aq = (f32x4){0.f, 0.f, 0.f, 0.f};
      aq = __builtin_amdgcn_mfma_f32_16x16x32_bf16(afr[rt][0], wB[0][0], aq, 0, 0, 0);
      aq = __builtin_amdgcn_mfma_f32_16x16x32_bf16(afr[rt][1], wB[0][1], aq, 0, 0, 0);
#pragma unroll
      for (int r = 0; r < 4; ++r)
        qs[(16 * rt + hi4 * 4 + r) * 68 + col] = (aq[r] + bq_c) * 0.25f;
    }
#pragma unroll
    for (int rt = 0; rt < 3; ++rt) {
      f32x4 ak = (f32x4){0.f, 0.f, 0.f, 0.f};
      ak = __builtin_amdgcn_mfma_f32_16x16x32_bf16(afr[rt][0], wB[1][0], ak, 0, 0, 0);
      ak = __builtin_amdgcn_mfma_f32_16x16x32_bf16(afr[rt][1], wB[1][1], ak, 0, 0, 0);
#pragma unroll
      for (int r = 0; r < 4; ++r)
        ksh[(16 * rt + hi4 * 4 + r) * 68 + col] = ak[r] + bk_c;
    }
#pragma unroll
    for (int rt = 0; rt < 3; ++rt) {
      f32x4 av = (f32x4){0.f, 0.f, 0.f, 0.f};
      av = __builtin_amdgcn_mfma_f32_16x16x32_bf16(afr[rt][0], wB[2][0], av, 0, 0, 0);
      av = __builtin_amdgcn_mfma_f32_16x16x32_bf16(afr[rt][1], wB[2][1], av, 0, 0, 0);
#pragma unroll
      for (int r = 0; r < 4; ++r)
        vs[(16 * rt + hi4 * 4 + r) * 68 + col] = f2b(av[r] + bv_c);
    }
    // prefetch next slice (flat loads off scalar base)
    if (it < 15) {
      const unsigned short* hp = hs + (size_t)(it + 1) * (N_ * H_);
#pragma unroll
      for (int k = 0; k < 3; ++k) pf[k] = *(const u64*)&hp[goff[k]];
    }
    __syncthreads();                          // B2: qkv ready

    // ---- softmax + PV: thread = (f, head, dq); o -> global directly ----
    {
      int f = tid >> 4, head = (tid >> 2) & 3, dq = tid & 3;
      int colb = head * 16 + dq * 4;
      f32x4 qv[3], kv[3];
      float vv[3][4];
#pragma unroll
      for (int qi = 0; qi < 3; ++qi) {
        int base = (3 * f + qi) * 68 + colb;
        qv[qi] = *(const f32x4*)&qs[base];
        kv[qi] = *(const f32x4*)&ksh[base];
        u64 uv = *(const u64*)&vs[base];
#pragma unroll
        for (int e = 0; e < 4; ++e)
          vv[qi][e] = b2f((unsigned short)(uv >> (16 * e)));
      }
      float s[3][3];
#pragma unroll
      for (int qi = 0; qi < 3; ++qi)
#pragma unroll
        for (int ki = 0; ki < 3; ++ki) {
          float a = qv[qi][0] * kv[ki][0] + qv[qi][1] * kv[ki][1]
                  + qv[qi][2] * kv[ki][2] + qv[qi][3] * kv[ki][3];
          a += __shfl_xor(a, 1, 64);
          a += __shfl_xor(a, 2, 64);
          s[qi][ki] = a;
        }
      const size_t abase = (size_t)it * NE_ + (size_t)bid * 48;
#pragma unroll
      for (int qi = 0; qi < 3; ++qi) {
        float mx = fmaxf(s[qi][0], fmaxf(s[qi][1], s[qi][2]));
        float e0 = __expf(s[qi][0] - mx), e1 = __expf(s[qi][1] - mx), e2 = __expf(s[qi][2] - mx);
        float inv = 1.f / (e0 + e1 + e2);
        e0 *= inv; e1 *= inv; e2 *= inv;
        int row = 3 * f + qi;
        u64 pack = 0;
#pragma unroll
        for (int e = 0; e < 4; ++e) {
          float o = e0 * vv[0][e] + e1 * vv[1][e] + e2 * vv[2][e];
          pack |= (u64)f2b(o) << (16 * e);
        }
        *(u64*)&a_edge[(abase + row) * H_ + colb] = pack;
      }
    }
    if (it < 15) __syncthreads();             // B3: qkv/bufrag reusable
  }
}

// ---------------------------------------------------------------------------
// Kernel 3 v4m: R8's verified head, halves MERGED — grid 4096 = 16 ls x 256.
// Inside byte-identical to R8 (u64 gather, rcp, Wo absorbed as MFMA GEMM).
// ---------------------------------------------------------------------------
__global__ __launch_bounds__(256) void k_head(
    const unsigned short* __restrict__ a_edge, // [16,NE,H] bf16 — o values
    const int* __restrict__ offs, const int* __restrict__ elist,
    const unsigned short* __restrict__ wT,     // [4][64][64]; m=3 is Wo
    const float* __restrict__ bo,
    const float* __restrict__ extra,
    const float* __restrict__ W1, const float* __restrict__ b1,
    const unsigned short* __restrict__ w1Tg,   // [64][64] bf16 transposed
    const float* __restrict__ W2, const float* __restrict__ b2,
    float* __restrict__ yg,                    // [T*B,KALL,H] f32, pre-zeroed
    float* __restrict__ logit)                 // [T,B,N] f32
{
  __shared__ __align__(16) short w1T[64 * STR];
  __shared__ __align__(16) short arow[64 * STR];
  __shared__ int offsS[65];
  __shared__ int eidS[512];
  __shared__ float hEx[64];
  __shared__ float w2s[64];
  __shared__ float hasES[64];
  __shared__ float red[4][64];

  const int tid = threadIdx.x;
  const int lane = tid & 63;
  const int w = tid >> 6;
  const int c15 = lane & 15;
  const int hi4 = lane >> 4;
  const int bid = blockIdx.x;
  const int ls = bid >> 8;             // slice 0..15
  const int tb = ls;
  const int nbase = (bid & 255) * 64;
  const int kall = nbase >> 12;

  // stage w1T from pre-converted w1Tg: 2 x 16-B copies per thread
#pragma unroll
  for (int c = 0; c < 2; ++c) {
    int lin = (c * 256 + tid) * 8;
    int row = lin >> 6, col = lin & 63;
    *(s16x8*)&w1T[row * STR + col] = *(const s16x8*)&w1Tg[lin];
  }
  if (tid < 65) offsS[tid] = offs[nbase + tid];
  if (tid < 64) {
    float s = b1[tid];
#pragma unroll
    for (int e = 0; e < 4; ++e)
      s += extra[(tb * KALL_ + kall) * DE_ + e] * W1[(64 + e) * 64 + tid];
    hEx[tid] = s;
    w2s[tid] = W2[tid];
  }
  // Wo B-fragments + bias in registers (coalesced 16-B loads from wT)
  s16x8 wo_b[2][4];
  float boc[4];
#pragma unroll
  for (int ct = 0; ct < 4; ++ct) {
    boc[ct] = bo[16 * ct + c15];
#pragma unroll
    for (int ks = 0; ks < 2; ++ks)
      wo_b[ks][ct] = *(const s16x8*)&wT[(192 + 16 * ct + c15) * 64 + ks * 32 + hi4 * 8];
  }
  // edge-range staging
  const int ebeg = offs[nbase];
  const int ecnt = offs[nbase + 64] - ebeg;
  const bool fast = (ecnt <= 512);
  if (tid == 0) eidS[0] = 0;           // safe dup slot even when ecnt == 0
  if (fast) {
    for (int j = tid; j < ecnt; j += 256) eidS[j] = elist[ebeg + j];
  }
  __syncthreads();

  const size_t ebase = (size_t)ls * NE_;
  if (fast) {
    const int cg = tid & 15;
#pragma unroll
    for (int ku = 0; ku < 4; ++ku) {
      const int r = ku * 16 + (tid >> 4);
      const int beg = offsS[r] - ebeg, end = offsS[r + 1] - ebeg;
      const int cnt = end - beg;
      const float inv = __builtin_amdgcn_rcpf(fmaxf((float)cnt, 1.f));
      f32x4 s = (f32x4){0.f, 0.f, 0.f, 0.f};
#pragma unroll
      for (int u = 0; u < 8; ++u) {
        int p = beg + u;
        bool valid = p < end;
        int pc = valid ? p : 0;        // dup -> eidS[0] row, L1-hot
        u64 v = *(const u64*)&a_edge[(ebase + eidS[pc]) * H_ + cg * 4];
        if (!valid) v = 0;             // 2 cndmasks; b2f(0)=0
        s[0] += b2f((unsigned short)v);
        s[1] += b2f((unsigned short)(v >> 16));
        s[2] += b2f((unsigned short)(v >> 32));
        s[3] += b2f((unsigned short)(v >> 48));
      }
      for (int p = beg + 8; p < end; ++p) {        // rare tail (cnt > 8)
        u64 v = *(const u64*)&a_edge[(ebase + eidS[p]) * H_ + cg * 4];
        s[0] += b2f((unsigned short)v);
        s[1] += b2f((unsigned short)(v >> 16));
        s[2] += b2f((unsigned short)(v >> 32));
        s[3] += b2f((unsigned short)(v >> 48));
      }
      u64 pk = 0;
#pragma unroll
      for (int e = 0; e < 4; ++e) pk |= (u64)f2b(s[e] * inv) << (16 * e);
      *(u64*)&arow[r * STR + cg * 4] = pk;
      if (cg == 0) hasES[r] = (cnt > 0) ? 1.f : 0.f;
    }
  } else {
    // fallback: direct-global dynamic loop (never taken for this input size)
    for (int r = w; r < 64; r += 4) {
      const int beg = offsS[r], end = offsS[r + 1];
      float s = 0.f;
      for (int p = beg; p < end; ++p)
        s += b2f(a_edge[(ebase + elist[p]) * H_ + lane]);
      float val = s / fmaxf((float)(end - beg), 1.f);
      arow[r * STR + lane] = (short)f2b(val);
      if (lane == 0) hasES[r] = (end > beg) ? 1.f : 0.f;
    }
  }
  __syncthreads();

  // ---- Wo GEMM: o-mean -> y; overwrite arow in place (wave-private rows,
  // same-wave DS ordering makes reads-before-writes safe) ----
  f32x4 acco[4];
#pragma unroll
  for (int ct = 0; ct < 4; ++ct) acco[ct] = (f32x4){0.f, 0.f, 0.f, 0.f};
#pragma unroll
  for (int ks = 0; ks < 2; ++ks) {
    int kb = ks * 32 + hi4 * 8;
    s16x8 af = *(const s16x8*)&arow[(16 * w + c15) * STR + kb];
#pragma unroll
    for (int ct = 0; ct < 4; ++ct)
      acco[ct] = __builtin_amdgcn_mfma_f32_16x16x32_bf16(af, wo_b[ks][ct], acco[ct], 0, 0, 0);
  }
  float sumy[4] = {0.f, 0.f, 0.f, 0.f};
#pragma unroll
  for (int r = 0; r < 4; ++r) {
    const int rowr = 16 * w + hi4 * 4 + r;
    const float hase = hasES[rowr];
#pragma unroll
    for (int ct = 0; ct < 4; ++ct) {
      float y = acco[ct][r] + hase * boc[ct];
      arow[rowr * STR + 16 * ct + c15] = (short)f2b(y);
      sumy[ct] += y;
    }
  }
#pragma unroll
  for (int ct = 0; ct < 4; ++ct) {
    sumy[ct] += __shfl_xor(sumy[ct], 16, 64);
    sumy[ct] += __shfl_xor(sumy[ct], 32, 64);
  }
  if (hi4 == 0) {
#pragma unroll
    for (int ct = 0; ct < 4; ++ct) red[w][16 * ct + c15] = sumy[ct];
  }

  // ---- W1 GEMM (reads own wave's arow_y rows; no barrier needed) ----
  f32x4 acc[4];
#pragma unroll
  for (int ct = 0; ct < 4; ++ct) acc[ct] = (f32x4){0.f, 0.f, 0.f, 0.f};
#pragma unroll
  for (int ks = 0; ks < 2; ++ks) {
    int kb = ks * 32 + hi4 * 8;
    s16x8 af = *(const s16x8*)&arow[(16 * w + c15) * STR + kb];
#pragma unroll
    for (int ct = 0; ct < 4; ++ct) {
      s16x8 bfr = *(const s16x8*)&w1T[(16 * ct + c15) * STR + kb];
      acc[ct] = __builtin_amdgcn_mfma_f32_16x16x32_bf16(af, bfr, acc[ct], 0, 0, 0);
    }
  }
  const float b2v = b2[0];
#pragma unroll
  for (int r = 0; r < 4; ++r) {
    float s = 0.f;
#pragma unroll
    for (int ct = 0; ct < 4; ++ct) {
      int colc = 16 * ct + c15;
      s += fmaxf(acc[ct][r] + hEx[colc], 0.f) * w2s[colc];
    }
    s += __shfl_xor(s, 1, 64);
    s += __shfl_xor(s, 2, 64);
    s += __shfl_xor(s, 4, 64);
    s += __shfl_xor(s, 8, 64);
    if (c15 == 0)
      logit[tb * N_ + nbase + 16 * w + hi4 * 4 + r] = s + b2v;
  }
  __syncthreads();
  if (tid < 64) {
    float sv = red[0][tid] + red[1][tid] + red[2][tid] + red[3][tid];
    atomicAdd(&yg[(tb * KALL_ + kall) * H_ + tid], sv);
  }
}

// ---------------------------------------------------------------------------
// Kernel 4: value head + h_global passthrough (f32)
// ---------------------------------------------------------------------------
__global__ __launch_bounds__(256) void k_final(
    const float* __restrict__ yg,
    const float* __restrict__ extra,
    const float* __restrict__ Wv1, const float* __restrict__ bv1,
    const float* __restrict__ hg_in,
    float* __restrict__ value_out,
    float* __restrict__ hg_out)
{
  const int tid = threadIdx.x;
  if (tid < 16) {
    const float bv = bv1[0];
    float v = 0.f;
    for (int kall = 0; kall < 4; ++kall) {
      float s = bv;
      for (int hh = 0; hh < 64; ++hh)
        s += (yg[(tid * KALL_ + kall) * H_ + hh] * (1.f / 4096.f)) * Wv1[hh];
      for (int e = 0; e < 4; ++e)
        s += extra[(tid * KALL_ + kall) * DE_ + e] * Wv1[64 + e];
      v += s;
    }
    value_out[tid] = v;
  }
  for (int i = tid; i < 1024; i += 256) hg_out[i] = hg_in[i];
}

// ---------------------------------------------------------------------------
// Workspace layout (134.7 MB; observed ws poison fill = 268 MB, fits):
//   yg     @ 0        : 16,384 B    f32 [T*B,KALL,H]
//   cnt    @ 16384    : 65,536 B    int [N]
//   offs   @ 81920    : 65,540 B    int [N+1]
//   cursor @ 147584   : 65,536 B    int [N]
//   elist  @ 213120   : 196,608 B   int [NE]
//   whTg   @ 409728   : 24,576 B    bf16 [192][64] permuted WhT
//   wT     @ 434304   : 32,768 B    bf16 [4][64][64] transposed Wq/Wk/Wv/Wo
//   w1Tg   @ 467072   : 8,192 B     bf16 [64][64] transposed W1
//   hs     @ 524288   : 33,554,432 B bf16 [T*B,N,H]
//   a_edge @ 34078720 : 100,663,296 B bf16 [16,NE,H] o-values (full run)
// ---------------------------------------------------------------------------
extern "C" void kernel_launch(void* const* d_in, const int* in_sizes, int n_in,
                              void* d_out, int out_size, void* d_ws, size_t ws_size,
                              hipStream_t stream)
{
  (void)in_sizes; (void)n_in; (void)out_size; (void)ws_size;
  const float* h0    = (const float*)d_in[0];
  const float* hg    = (const float*)d_in[1];
  const float* x     = (const float*)d_in[2];
  const float* extra = (const float*)d_in[3];
  const int*   dn    = (const int*)d_in[4];
  const int*   idx   = (const int*)d_in[5];
  const float* nnz   = (const float*)d_in[6];
  const float* Wi    = (const float*)d_in[7];
  const float* bi    = (const float*)d_in[8];
  const float* Wh    = (const float*)d_in[9];
  const float* bhn   = (const float*)d_in[10];
  const float* Wq    = (const float*)d_in[11];
  const float* bq    = (const float*)d_in[12];
  const float* Wk    = (const float*)d_in[13];
  const float* bk    = (const float*)d_in[14];
  const float* Wv    = (const float*)d_in[15];
  const float* bv    = (const float*)d_in[16];
  const float* Wo    = (const float*)d_in[17];
  const float* bo    = (const float*)d_in[18];
  const float* W1    = (const float*)d_in[19];
  const float* b1    = (const float*)d_in[20];
  const float* W2    = (const float*)d_in[21];
  const float* b2    = (const float*)d_in[22];
  const float* Wv1   = (const float*)d_in[23];
  const float* bv1   = (const float*)d_in[24];
  (void)nnz;

  float* out = (float*)d_out;
  float* out_hfin  = out;                 // [B,N,H]    4194304
  float* out_hg    = out + 4194304;       // [B,K,DOUT]    1024
  float* out_logit = out + 4195328;       // [T,B,N]     262144
  float* out_value = out + 4457472;       // [T,B]           16

  char* wsb = (char*)d_ws;
  float*          yg     = (float*)wsb;
  int*            cnt    = (int*)(wsb + 16384);
  int*            offs   = (int*)(wsb + 81920);
  int*            cursor = (int*)(wsb + 147584);
  int*            elist  = (int*)(wsb + 213120);
  unsigned short* whTg   = (unsigned short*)(wsb + 409728);
  unsigned short* wT     = (unsigned short*)(wsb + 434304);
  unsigned short* w1Tg   = (unsigned short*)(wsb + 467072);
  unsigned short* hs     = (unsigned short*)(wsb + 524288);
  unsigned short* a_edge = (unsigned short*)(wsb + 34078720);

  hipMemsetAsync(wsb, 0, 81920, stream);      // yg + cnt
  k_prep<<<320, 256, 0, stream>>>(idx, cnt, Wh, whTg, Wq, Wk, Wv, Wo, wT,
                                  W1, w1Tg);
  k_csr_scan<<<1, 256, 0, stream>>>(cnt, offs, cursor);
  k_csr_fill<<<192, 256, 0, stream>>>(idx, cursor, elist);
  k_gru<<<512, 512, 0, stream>>>(h0, x, dn, whTg, Wi, bi, bhn, hs, out_hfin);
  k_attn<<<1024, 256, 0, stream>>>(hs, idx, wT, bq, bk, bv, a_edge);
  k_head<<<4096, 256, 0, stream>>>(a_edge, offs, elist, wT, bo, extra,
                                   W1, b1, w1Tg, W2, b2, yg, out_logit);
  k_final<<<1, 256, 0, stream>>>(yg, extra, Wv1, bv1, hg, out_value, out_hg);
}